// Round 8
// baseline (397.574 us; speedup 1.0000x reference)
//
#include <hip/hip_runtime.h>
#include <math.h>

// Swin block, fused bf16-MFMA kernel: hoisted B-frags, register-transposed MLP, 5 barriers.
// B=64, H=W=56, C=96, WS=7, SS=3, NH=3, HD=32, N=49 (padded 64), nW=64.

#define CDIM 96
#define SCALE_QK 0.17677669529663687f  // 32^-0.5

typedef __attribute__((ext_vector_type(8))) short bf16x8;
typedef __attribute__((ext_vector_type(4))) float f32x4;
typedef __attribute__((ext_vector_type(2))) unsigned int u32x2;
typedef __attribute__((ext_vector_type(4))) unsigned int u32x4;

__device__ inline unsigned short f2b(float f) {
    union { float f; unsigned u; } v; v.f = f;
    unsigned r = v.u + 0x7FFF + ((v.u >> 16) & 1);   // RNE
    return (unsigned short)(r >> 16);
}
__device__ inline unsigned pkcvt(float a, float b) {   // low16=bf16(a), high16=bf16(b)
    unsigned d;
    asm("v_cvt_pk_bf16_f32 %0, %1, %2" : "=v"(d) : "v"(a), "v"(b));
    return d;
}
__device__ inline float bitsf(unsigned u) {
    union { unsigned u; float f; } v; v.u = u; return v.f;
}
__device__ inline bf16x8 mk8(unsigned d0, unsigned d1, unsigned d2, unsigned d3) {
    union { u32x4 u; bf16x8 h; } v;
    v.u = (u32x4){d0, d1, d2, d3};
    return v.h;
}

// ---------------- Kernel 0a: weights fp32 -> bf16 ----------------
__global__ __launch_bounds__(256) void conv_w_kernel(
    const float* __restrict__ qkv_w, const float* __restrict__ proj_w,
    const float* __restrict__ fc1_w, const float* __restrict__ fc2_w,
    unsigned short* __restrict__ ws)
{
    const int i = blockIdx.x * 256 + threadIdx.x;
    if (i < 27648)       ws[i] = f2b(qkv_w[i]);
    else if (i < 36864)  ws[i] = f2b(proj_w[i - 27648]);
    else if (i < 73728)  ws[i] = f2b(fc1_w[i - 36864]);
    else if (i < 110592) ws[i] = f2b(fc2_w[i - 73728]);
}

// ---------------- Kernel 0b: bias+mask in MFMA C-fragment layout, bf16 ----------------
__global__ __launch_bounds__(256) void build_bmfrag_kernel(
    const float* __restrict__ attn_mask, const float* __restrict__ rel_bias_table,
    const int* __restrict__ rel_index, unsigned short* __restrict__ bmf)
{
    const int i = blockIdx.x * 256 + threadIdx.x;   // 196608 total
    const int lane = i & 63;
    const int mt = (i >> 6) & 3;
    const int kt = (i >> 8) & 3;
    const int t3 = i >> 10;                          // widx*3 + h
    const int h = t3 % 3, widx = t3 / 3;
    const int q = mt * 16 + (lane & 15);
    const int kb = kt * 16 + (lane >> 4) * 4;
    float vv[4];
    #pragma unroll
    for (int rr = 0; rr < 4; ++rr) {
        const int k = kb + rr;
        float val = -1.0e30f;
        if (q < 49 && k < 49) {
            const int idx = q * 49 + k;
            val = rel_bias_table[rel_index[idx] * 3 + h] + attn_mask[widx * 2401 + idx];
        }
        vv[rr] = val;
    }
    u32x2 pw;
    pw.x = (unsigned)f2b(vv[0]) | ((unsigned)f2b(vv[1]) << 16);
    pw.y = (unsigned)f2b(vv[2]) | ((unsigned)f2b(vv[3]) << 16);
    *(u32x2*)(bmf + (size_t)i * 4) = pw;
}

// ---------------- Fused kernel ----------------
// LDS (53760 B): xt [64][104]u16 @0 | qs [64][104] @13312 | kss [64][104] @26624 |
//                vs [96][72] @39936.  Alias after attn: hbuf [64][101]f32 @26624.
__global__ __launch_bounds__(512, 6) void swin_fused(
    const float* __restrict__ x,
    const float* __restrict__ ln1_g, const float* __restrict__ ln1_b,
    const float* __restrict__ qkv_b, const float* __restrict__ proj_b,
    const float* __restrict__ ln2_g, const float* __restrict__ ln2_b,
    const float* __restrict__ fc1_b, const float* __restrict__ fc2_b,
    const unsigned short* __restrict__ wqkv,   // [288][96] bf16
    const unsigned short* __restrict__ wproj,  // [96][96] bf16
    const unsigned short* __restrict__ wfc1,   // [384][96] bf16
    const unsigned short* __restrict__ wfc2,   // [96][384] bf16
    const unsigned short* __restrict__ bmfrag,
    float* __restrict__ out)
{
    __shared__ __align__(16) unsigned char smem[53760];
    unsigned short (*xt)[104]  = (unsigned short(*)[104])(smem);
    unsigned short (*qs)[104]  = (unsigned short(*)[104])(smem + 13312);
    unsigned short (*kss)[104] = (unsigned short(*)[104])(smem + 26624);
    unsigned short (*vs)[72]   = (unsigned short(*)[72])(smem + 39936);
    float          (*hbuf)[101]= (float(*)[101])(smem + 26624);
    unsigned short (*xs)[104]  = xt;

    const int w = blockIdx.x, b = w >> 6, widx = w & 63;
    const int wi = widx >> 3, wj = widx & 7;
    const int tid = threadIdx.x, wave = tid >> 6, lane = tid & 63;
    const int l15 = lane & 15, lk = (lane >> 4) * 8, g4 = (lane >> 4) * 4;
    const int rb = wave & 3, half = wave >> 2;   // row-block / task-half per wave

    // ---- Phase 1: LN1 + shifted gather (roll -3,-3); 8 threads per row ----
    {
        const int n = tid >> 3, oc = tid & 7;
        if (n < 49) {
            const int p = n / 7, qq = n - 7 * p;
            int sr = wi * 7 + p + 3;   if (sr >= 56) sr -= 56;
            int scl = wj * 7 + qq + 3; if (scl >= 56) scl -= 56;
            const float* xr = x + ((size_t)b * 3136 + (size_t)(sr * 56 + scl)) * CDIM + oc * 12;
            float vals[12];
            float s = 0.f, ss2 = 0.f;
            #pragma unroll
            for (int i = 0; i < 3; ++i) {
                const float4 f = *(const float4*)(xr + i * 4);
                vals[i*4+0] = f.x; vals[i*4+1] = f.y; vals[i*4+2] = f.z; vals[i*4+3] = f.w;
                s += f.x + f.y + f.z + f.w;
                ss2 += f.x*f.x + f.y*f.y + f.z*f.z + f.w*f.w;
            }
            s += __shfl_xor(s, 1);  ss2 += __shfl_xor(ss2, 1);
            s += __shfl_xor(s, 2);  ss2 += __shfl_xor(ss2, 2);
            s += __shfl_xor(s, 4);  ss2 += __shfl_xor(ss2, 4);
            const float mean = s * (1.f / 96.f);
            const float rstd = rsqrtf(ss2 * (1.f / 96.f) - mean * mean + 1e-5f);
            #pragma unroll
            for (int v4 = 0; v4 < 3; ++v4) {
                const float4 gg = *(const float4*)(ln1_g + oc * 12 + v4 * 4);
                const float4 bb = *(const float4*)(ln1_b + oc * 12 + v4 * 4);
                u32x2 pv;
                pv.x = pkcvt((vals[v4*4+0]-mean)*rstd*gg.x + bb.x,
                             (vals[v4*4+1]-mean)*rstd*gg.y + bb.y);
                pv.y = pkcvt((vals[v4*4+2]-mean)*rstd*gg.z + bb.z,
                             (vals[v4*4+3]-mean)*rstd*gg.w + bb.w);
                *(u32x2*)&xt[n][oc * 12 + v4 * 4] = pv;
            }
        } else {
            const u32x2 z = {0u, 0u};
            #pragma unroll
            for (int v4 = 0; v4 < 3; ++v4) *(u32x2*)&xt[n][oc * 12 + v4 * 4] = z;
        }
    }
    __syncthreads();

    // ---- Phase 2: qkv projection; wave owns xt row-block rb, B-frags hoisted ----
    {
        const bf16x8 bx0 = *(const bf16x8*)&xt[rb * 16 + l15][lk];
        const bf16x8 bx1 = *(const bf16x8*)&xt[rb * 16 + l15][32 + lk];
        const bf16x8 bx2 = *(const bf16x8*)&xt[rb * 16 + l15][64 + lk];
        // Q/K swapped GEMM: 6 feat-tiles per wave
        #pragma unroll
        for (int j = 0; j < 6; ++j) {
            const int qt = half * 6 + j;             // 0..11 (feats 0..191)
            const unsigned short* wr = wqkv + (size_t)(qt * 16 + l15) * 96;
            f32x4 acc = {0.f, 0.f, 0.f, 0.f};
            acc = __builtin_amdgcn_mfma_f32_16x16x32_bf16(*(const bf16x8*)(wr + lk),      bx0, acc, 0, 0, 0);
            acc = __builtin_amdgcn_mfma_f32_16x16x32_bf16(*(const bf16x8*)(wr + 32 + lk), bx1, acc, 0, 0, 0);
            acc = __builtin_amdgcn_mfma_f32_16x16x32_bf16(*(const bf16x8*)(wr + 64 + lk), bx2, acc, 0, 0, 0);
            const int f0 = qt * 16 + g4;
            const float4 bias = *(const float4*)(qkv_b + f0);
            const int tok = rb * 16 + l15;
            u32x2 pw;
            if (qt < 6) {                            // Q (scale folded)
                pw.x = pkcvt((acc[0] + bias.x) * SCALE_QK, (acc[1] + bias.y) * SCALE_QK);
                pw.y = pkcvt((acc[2] + bias.z) * SCALE_QK, (acc[3] + bias.w) * SCALE_QK);
                *(u32x2*)&qs[tok][f0] = pw;
            } else {                                 // K
                pw.x = pkcvt(acc[0] + bias.x, acc[1] + bias.y);
                pw.y = pkcvt(acc[2] + bias.z, acc[3] + bias.w);
                *(u32x2*)&kss[tok][f0 - 96] = pw;
            }
        }
        // V normal GEMM: 3 vfeat-tiles per wave (A-frag == bx)
        #pragma unroll
        for (int j = 0; j < 3; ++j) {
            const int vt = half * 3 + j;             // 0..5
            const unsigned short* wr = wqkv + (size_t)(192 + vt * 16 + l15) * 96;
            f32x4 acc = {0.f, 0.f, 0.f, 0.f};
            acc = __builtin_amdgcn_mfma_f32_16x16x32_bf16(bx0, *(const bf16x8*)(wr + lk),      acc, 0, 0, 0);
            acc = __builtin_amdgcn_mfma_f32_16x16x32_bf16(bx1, *(const bf16x8*)(wr + 32 + lk), acc, 0, 0, 0);
            acc = __builtin_amdgcn_mfma_f32_16x16x32_bf16(bx2, *(const bf16x8*)(wr + 64 + lk), acc, 0, 0, 0);
            const float bias = qkv_b[192 + vt * 16 + l15];
            u32x2 pw;
            pw.x = pkcvt(acc[0] + bias, acc[1] + bias);
            pw.y = pkcvt(acc[2] + bias, acc[3] + bias);
            *(u32x2*)&vs[vt * 16 + l15][rb * 16 + g4] = pw;
        }
    }
    __syncthreads();

    // ---- Phase 3: swapped QK^T + register softmax + in-register P exchange + PV ----
    #pragma unroll
    for (int it = 0; it < 2; ++it) {
        const int ui = wave + 8 * it;
        if (ui < 12) {
            const int h = ui >> 2, mt = ui & 3;
            const bf16x8 bq = *(const bf16x8*)&qs[mt * 16 + l15][h * 32 + lk];
            const unsigned short* bmb = bmfrag + (size_t)(widx * 3 + h) * 4096 + mt * 256;
            f32x4 s[4];
            #pragma unroll
            for (int kt = 0; kt < 4; ++kt) {
                const bf16x8 ak = *(const bf16x8*)&kss[kt * 16 + l15][h * 32 + lk];
                const u32x2 cw = *(const u32x2*)(bmb + kt * 1024 + lane * 4);
                f32x4 c;
                c[0] = bitsf(cw.x << 16); c[1] = bitsf(cw.x & 0xffff0000u);
                c[2] = bitsf(cw.y << 16); c[3] = bitsf(cw.y & 0xffff0000u);
                s[kt] = __builtin_amdgcn_mfma_f32_16x16x32_bf16(ak, bq, c, 0, 0, 0);
            }
            float mx = s[0][0];
            #pragma unroll
            for (int kt = 0; kt < 4; ++kt)
                #pragma unroll
                for (int rr = 0; rr < 4; ++rr) mx = fmaxf(mx, s[kt][rr]);
            mx = fmaxf(mx, __shfl_xor(mx, 16));
            mx = fmaxf(mx, __shfl_xor(mx, 32));
            float sum = 0.f;
            #pragma unroll
            for (int kt = 0; kt < 4; ++kt)
                #pragma unroll
                for (int rr = 0; rr < 4; ++rr) {
                    const float e = __expf(s[kt][rr] - mx);
                    s[kt][rr] = e; sum += e;
                }
            sum += __shfl_xor(sum, 16);
            sum += __shfl_xor(sum, 32);
            const float inv = __fdividef(1.0f, sum);
            unsigned pk00 = pkcvt(s[0][0], s[0][1]), pk01 = pkcvt(s[0][2], s[0][3]);
            unsigned pk10 = pkcvt(s[1][0], s[1][1]), pk11 = pkcvt(s[1][2], s[1][3]);
            unsigned pk20 = pkcvt(s[2][0], s[2][1]), pk21 = pkcvt(s[2][2], s[2][3]);
            unsigned pk30 = pkcvt(s[3][0], s[3][1]), pk31 = pkcvt(s[3][2], s[3][3]);
            const int srcA = ((lane >> 4) & 1) * 32 + l15;
            const int srcB = srcA + 16;
            const bool hi = (lane & 32) != 0;
            unsigned a0, a1, a2, a3, b0, b1, b2, b3;
            a0 = __shfl(pk00, srcA); a1 = __shfl(pk01, srcA);
            a2 = __shfl(pk10, srcA); a3 = __shfl(pk11, srcA);
            b0 = __shfl(pk00, srcB); b1 = __shfl(pk01, srcB);
            b2 = __shfl(pk10, srcB); b3 = __shfl(pk11, srcB);
            const bf16x8 pb0 = mk8(hi ? a2 : a0, hi ? a3 : a1, hi ? b2 : b0, hi ? b3 : b1);
            a0 = __shfl(pk20, srcA); a1 = __shfl(pk21, srcA);
            a2 = __shfl(pk30, srcA); a3 = __shfl(pk31, srcA);
            b0 = __shfl(pk20, srcB); b1 = __shfl(pk21, srcB);
            b2 = __shfl(pk30, srcB); b3 = __shfl(pk31, srcB);
            const bf16x8 pb1 = mk8(hi ? a2 : a0, hi ? a3 : a1, hi ? b2 : b0, hi ? b3 : b1);
            f32x4 o0 = {0.f,0.f,0.f,0.f}, o1 = {0.f,0.f,0.f,0.f};
            {
                const bf16x8 v00 = *(const bf16x8*)&vs[h * 32 + l15][lk];
                const bf16x8 v01 = *(const bf16x8*)&vs[h * 32 + l15][32 + lk];
                const bf16x8 v10 = *(const bf16x8*)&vs[h * 32 + 16 + l15][lk];
                const bf16x8 v11 = *(const bf16x8*)&vs[h * 32 + 16 + l15][32 + lk];
                o0 = __builtin_amdgcn_mfma_f32_16x16x32_bf16(v00, pb0, o0, 0, 0, 0);
                o0 = __builtin_amdgcn_mfma_f32_16x16x32_bf16(v01, pb1, o0, 0, 0, 0);
                o1 = __builtin_amdgcn_mfma_f32_16x16x32_bf16(v10, pb0, o1, 0, 0, 0);
                o1 = __builtin_amdgcn_mfma_f32_16x16x32_bf16(v11, pb1, o1, 0, 0, 0);
            }
            u32x2 ow;
            ow.x = pkcvt(o0[0] * inv, o0[1] * inv);
            ow.y = pkcvt(o0[2] * inv, o0[3] * inv);
            *(u32x2*)&xt[mt * 16 + l15][h * 32 + g4] = ow;
            ow.x = pkcvt(o1[0] * inv, o1[1] * inv);
            ow.y = pkcvt(o1[2] * inv, o1[3] * inv);
            *(u32x2*)&xt[mt * 16 + l15][h * 32 + 16 + g4] = ow;
        }
    }
    __syncthreads();

    // ---- Phase 4: proj + x-residual -> hbuf (fp32); A-frags hoisted; pad rows -> 0 ----
    {
        const bf16x8 a0 = *(const bf16x8*)&xt[rb * 16 + l15][lk];
        const bf16x8 a1 = *(const bf16x8*)&xt[rb * 16 + l15][32 + lk];
        const bf16x8 a2 = *(const bf16x8*)&xt[rb * 16 + l15][64 + lk];
        #pragma unroll
        for (int j = 0; j < 3; ++j) {
            const int nt = half * 3 + j;
            const unsigned short* wr = wproj + (size_t)(nt * 16 + l15) * 96;
            f32x4 acc = {0.f, 0.f, 0.f, 0.f};
            acc = __builtin_amdgcn_mfma_f32_16x16x32_bf16(a0, *(const bf16x8*)(wr + lk),      acc, 0, 0, 0);
            acc = __builtin_amdgcn_mfma_f32_16x16x32_bf16(a1, *(const bf16x8*)(wr + 32 + lk), acc, 0, 0, 0);
            acc = __builtin_amdgcn_mfma_f32_16x16x32_bf16(a2, *(const bf16x8*)(wr + 64 + lk), acc, 0, 0, 0);
            const int colf = nt * 16 + l15;
            const float pb = proj_b[colf];
            #pragma unroll
            for (int rr = 0; rr < 4; ++rr) {
                const int n = rb * 16 + g4 + rr;
                if (n < 49) {
                    const int p = n / 7, q = n - 7 * p;
                    int sr = wi * 7 + p + 3;  if (sr >= 56) sr -= 56;
                    int scl = wj * 7 + q + 3; if (scl >= 56) scl -= 56;
                    const size_t base = ((size_t)b * 3136 + (size_t)(sr * 56 + scl)) * CDIM + colf;
                    hbuf[n][colf] = acc[rr] + pb + x[base];
                } else {
                    hbuf[n][colf] = 0.f;
                }
            }
        }
    }
    __syncthreads();

    // ---- Phase 5: LN2 hbuf -> xs (bf16) ----
    {
        const int n = tid >> 3, oc = tid & 7;
        float vals[12];
        float s = 0.f, ss2 = 0.f;
        #pragma unroll
        for (int i = 0; i < 3; ++i) {
            const float4 f = *(const float4*)&hbuf[n][oc * 12 + i * 4];
            vals[i*4+0] = f.x; vals[i*4+1] = f.y; vals[i*4+2] = f.z; vals[i*4+3] = f.w;
            s += f.x + f.y + f.z + f.w;
            ss2 += f.x*f.x + f.y*f.y + f.z*f.z + f.w*f.w;
        }
        s += __shfl_xor(s, 1);  ss2 += __shfl_xor(ss2, 1);
        s += __shfl_xor(s, 2);  ss2 += __shfl_xor(ss2, 2);
        s += __shfl_xor(s, 4);  ss2 += __shfl_xor(ss2, 4);
        const float mean = s * (1.f / 96.f);
        const float rstd = rsqrtf(ss2 * (1.f / 96.f) - mean * mean + 1e-5f);
        #pragma unroll
        for (int v4 = 0; v4 < 3; ++v4) {
            const float4 gg = *(const float4*)(ln2_g + oc * 12 + v4 * 4);
            const float4 bb = *(const float4*)(ln2_b + oc * 12 + v4 * 4);
            u32x2 pv;
            pv.x = pkcvt((vals[v4*4+0]-mean)*rstd*gg.x + bb.x,
                         (vals[v4*4+1]-mean)*rstd*gg.y + bb.y);
            pv.y = pkcvt((vals[v4*4+2]-mean)*rstd*gg.z + bb.z,
                         (vals[v4*4+3]-mean)*rstd*gg.w + bb.w);
            *(u32x2*)&xs[n][oc * 12 + v4 * 4] = pv;
        }
    }
    __syncthreads();

    // ---- Phase 6: MLP, full-K per wave, m1 register-transposed (no LDS, no barriers) ----
    {
        const bf16x8 mbx0 = *(const bf16x8*)&xs[rb * 16 + l15][lk];
        const bf16x8 mbx1 = *(const bf16x8*)&xs[rb * 16 + l15][32 + lk];
        const bf16x8 mbx2 = *(const bf16x8*)&xs[rb * 16 + l15][64 + lk];
        f32x4 facc0 = {0.f,0.f,0.f,0.f}, facc1 = {0.f,0.f,0.f,0.f}, facc2 = {0.f,0.f,0.f,0.f};
        const int ct0 = half * 3;
        const int srcA = ((lane >> 4) & 1) * 32 + l15;
        const int srcB = srcA + 16;
        const bool hi = (lane & 32) != 0;
        #pragma unroll
        for (int kc = 0; kc < 12; ++kc) {
            const unsigned short* w0 = wfc1 + (size_t)(kc * 32 + l15) * 96;
            const unsigned short* w1 = wfc1 + (size_t)(kc * 32 + 16 + l15) * 96;
            f32x4 s0 = {0.f,0.f,0.f,0.f}, s1 = {0.f,0.f,0.f,0.f};
            s0 = __builtin_amdgcn_mfma_f32_16x16x32_bf16(*(const bf16x8*)(w0 + lk),      mbx0, s0, 0, 0, 0);
            s0 = __builtin_amdgcn_mfma_f32_16x16x32_bf16(*(const bf16x8*)(w0 + 32 + lk), mbx1, s0, 0, 0, 0);
            s0 = __builtin_amdgcn_mfma_f32_16x16x32_bf16(*(const bf16x8*)(w0 + 64 + lk), mbx2, s0, 0, 0, 0);
            s1 = __builtin_amdgcn_mfma_f32_16x16x32_bf16(*(const bf16x8*)(w1 + lk),      mbx0, s1, 0, 0, 0);
            s1 = __builtin_amdgcn_mfma_f32_16x16x32_bf16(*(const bf16x8*)(w1 + 32 + lk), mbx1, s1, 0, 0, 0);
            s1 = __builtin_amdgcn_mfma_f32_16x16x32_bf16(*(const bf16x8*)(w1 + 64 + lk), mbx2, s1, 0, 0, 0);
            const float4 bv0 = *(const float4*)(fc1_b + kc * 32 + g4);
            const float4 bv1 = *(const float4*)(fc1_b + kc * 32 + 16 + g4);
            const float* b0p = &bv0.x;
            const float* b1p = &bv1.x;
            float ge0[4], ge1[4];
            #pragma unroll
            for (int rr = 0; rr < 4; ++rr) {
                float u = s0[rr] + b0p[rr];
                float u2 = u * u;
                float n2y = u * (-1.5957691216f - 0.0713548162f * u2);
                ge0[rr] = __fdividef(u, 1.f + __expf(n2y));
                u = s1[rr] + b1p[rr];
                u2 = u * u;
                n2y = u * (-1.5957691216f - 0.0713548162f * u2);
                ge1[rr] = __fdividef(u, 1.f + __expf(n2y));
            }
            const unsigned pk00 = pkcvt(ge0[0], ge0[1]), pk01 = pkcvt(ge0[2], ge0[3]);
            const unsigned pk10 = pkcvt(ge1[0], ge1[1]), pk11 = pkcvt(ge1[2], ge1[3]);
            const unsigned a0 = __shfl(pk00, srcA), a1 = __shfl(pk01, srcA);
            const unsigned a2 = __shfl(pk10, srcA), a3 = __shfl(pk11, srcA);
            const unsigned b0 = __shfl(pk00, srcB), b1 = __shfl(pk01, srcB);
            const unsigned b2 = __shfl(pk10, srcB), b3 = __shfl(pk11, srcB);
            const bf16x8 pb = mk8(hi ? a2 : a0, hi ? a3 : a1, hi ? b2 : b0, hi ? b3 : b1);
            const unsigned short* w2 = wfc2 + kc * 32 + lk;
            facc0 = __builtin_amdgcn_mfma_f32_16x16x32_bf16(
                *(const bf16x8*)(w2 + (size_t)(ct0 * 16 + l15) * 384), pb, facc0, 0, 0, 0);
            facc1 = __builtin_amdgcn_mfma_f32_16x16x32_bf16(
                *(const bf16x8*)(w2 + (size_t)(ct0 * 16 + 16 + l15) * 384), pb, facc1, 0, 0, 0);
            facc2 = __builtin_amdgcn_mfma_f32_16x16x32_bf16(
                *(const bf16x8*)(w2 + (size_t)(ct0 * 16 + 32 + l15) * 384), pb, facc2, 0, 0, 0);
        }
        // epilogue: out = h + fc2 + b2 (wave owns token block rb, cout half ct0*16..+47)
        const int n = rb * 16 + l15;
        if (n < 49) {
            const int p = n / 7, q = n - 7 * p;
            int sr = wi * 7 + p + 3;  if (sr >= 56) sr -= 56;
            int scl = wj * 7 + q + 3; if (scl >= 56) scl -= 56;
            float* ob = out + ((size_t)b * 3136 + (size_t)(sr * 56 + scl)) * CDIM;
            #pragma unroll
            for (int j = 0; j < 3; ++j) {
                const int cb = (ct0 + j) * 16 + g4;
                const float4 hv  = *(const float4*)&hbuf[n][cb];
                const float4 b2v = *(const float4*)(fc2_b + cb);
                const f32x4 fa = (j == 0) ? facc0 : (j == 1) ? facc1 : facc2;
                float4 o4;
                o4.x = hv.x + fa[0] + b2v.x;
                o4.y = hv.y + fa[1] + b2v.y;
                o4.z = hv.z + fa[2] + b2v.z;
                o4.w = hv.w + fa[3] + b2v.w;
                *(float4*)(ob + cb) = o4;
            }
        }
    }
}

extern "C" void kernel_launch(void* const* d_in, const int* in_sizes, int n_in,
                              void* d_out, int out_size, void* d_ws, size_t ws_size,
                              hipStream_t stream) {
    (void)n_in; (void)out_size; (void)ws_size;
    const float* x        = (const float*)d_in[0];
    const float* attn_msk = (const float*)d_in[1];
    const float* ln1_g    = (const float*)d_in[2];
    const float* ln1_b    = (const float*)d_in[3];
    const float* qkv_w    = (const float*)d_in[4];
    const float* qkv_b    = (const float*)d_in[5];
    const float* rel_tab  = (const float*)d_in[6];
    const int*   rel_idx  = (const int*)d_in[7];
    const float* proj_w   = (const float*)d_in[8];
    const float* proj_b   = (const float*)d_in[9];
    const float* ln2_g    = (const float*)d_in[10];
    const float* ln2_b    = (const float*)d_in[11];
    const float* fc1_w    = (const float*)d_in[12];
    const float* fc1_b    = (const float*)d_in[13];
    const float* fc2_w    = (const float*)d_in[14];
    const float* fc2_b    = (const float*)d_in[15];
    float* out = (float*)d_out;
    unsigned short* wsb = (unsigned short*)d_ws;
    unsigned short* bmf = wsb + 110592;

    const int B = in_sizes[0] / (3136 * 96);   // 64

    conv_w_kernel<<<(110592 + 255) / 256, 256, 0, stream>>>(qkv_w, proj_w, fc1_w, fc2_w, wsb);
    build_bmfrag_kernel<<<196608 / 256, 256, 0, stream>>>(attn_msk, rel_tab, rel_idx, bmf);

    swin_fused<<<B * 64, 512, 0, stream>>>(
        x, ln1_g, ln1_b, qkv_b, proj_b, ln2_g, ln2_b, fc1_b, fc2_b,
        wsb, wsb + 27648, wsb + 36864, wsb + 73728, bmf, out);
}

// Round 9
// 342.902 us; speedup vs baseline: 1.1594x; 1.1594x over previous
//
#include <hip/hip_runtime.h>
#include <math.h>

// Swin block, fused bf16-MFMA kernel. R9: R7 attention + R6 MLP (reverted) + setprio.
// B=64, H=W=56, C=96, WS=7, SS=3, NH=3, HD=32, N=49 (padded 64), nW=64.

#define CDIM 96
#define SCALE_QK 0.17677669529663687f  // 32^-0.5

typedef __attribute__((ext_vector_type(8))) short bf16x8;
typedef __attribute__((ext_vector_type(4))) float f32x4;
typedef __attribute__((ext_vector_type(2))) unsigned int u32x2;
typedef __attribute__((ext_vector_type(4))) unsigned int u32x4;

__device__ inline unsigned short f2b(float f) {
    union { float f; unsigned u; } v; v.f = f;
    unsigned r = v.u + 0x7FFF + ((v.u >> 16) & 1);   // RNE
    return (unsigned short)(r >> 16);
}
__device__ inline unsigned pkcvt(float a, float b) {   // low16=bf16(a), high16=bf16(b)
    unsigned d;
    asm("v_cvt_pk_bf16_f32 %0, %1, %2" : "=v"(d) : "v"(a), "v"(b));
    return d;
}
__device__ inline float bitsf(unsigned u) {
    union { unsigned u; float f; } v; v.u = u; return v.f;
}
__device__ inline bf16x8 mk8(unsigned d0, unsigned d1, unsigned d2, unsigned d3) {
    union { u32x4 u; bf16x8 h; } v;
    v.u = (u32x4){d0, d1, d2, d3};
    return v.h;
}

// ---------------- Kernel 0a: weights fp32 -> bf16 ----------------
__global__ __launch_bounds__(256) void conv_w_kernel(
    const float* __restrict__ qkv_w, const float* __restrict__ proj_w,
    const float* __restrict__ fc1_w, const float* __restrict__ fc2_w,
    unsigned short* __restrict__ ws)
{
    const int i = blockIdx.x * 256 + threadIdx.x;
    if (i < 27648)       ws[i] = f2b(qkv_w[i]);
    else if (i < 36864)  ws[i] = f2b(proj_w[i - 27648]);
    else if (i < 73728)  ws[i] = f2b(fc1_w[i - 36864]);
    else if (i < 110592) ws[i] = f2b(fc2_w[i - 73728]);
}

// ---------------- Kernel 0b: bias+mask in MFMA C-fragment layout, bf16 ----------------
__global__ __launch_bounds__(256) void build_bmfrag_kernel(
    const float* __restrict__ attn_mask, const float* __restrict__ rel_bias_table,
    const int* __restrict__ rel_index, unsigned short* __restrict__ bmf)
{
    const int i = blockIdx.x * 256 + threadIdx.x;   // 196608 total
    const int lane = i & 63;
    const int mt = (i >> 6) & 3;
    const int kt = (i >> 8) & 3;
    const int t3 = i >> 10;                          // widx*3 + h
    const int h = t3 % 3, widx = t3 / 3;
    const int q = mt * 16 + (lane & 15);
    const int kb = kt * 16 + (lane >> 4) * 4;
    float vv[4];
    #pragma unroll
    for (int rr = 0; rr < 4; ++rr) {
        const int k = kb + rr;
        float val = -1.0e30f;
        if (q < 49 && k < 49) {
            const int idx = q * 49 + k;
            val = rel_bias_table[rel_index[idx] * 3 + h] + attn_mask[widx * 2401 + idx];
        }
        vv[rr] = val;
    }
    u32x2 pw;
    pw.x = (unsigned)f2b(vv[0]) | ((unsigned)f2b(vv[1]) << 16);
    pw.y = (unsigned)f2b(vv[2]) | ((unsigned)f2b(vv[3]) << 16);
    *(u32x2*)(bmf + (size_t)i * 4) = pw;
}

// ---------------- Fused kernel ----------------
// LDS (53760 B): xt [64][104]u16 @0 | qs [64][104] @13312 | kss [64][104] @26624 |
//                vs [96][72] @39936.
// Aliases after attn: m1 [64][104]u16 @13312 (qs), hbuf [64][101]f32 @26624 (kss+vs).
__global__ __launch_bounds__(512, 6) void swin_fused(
    const float* __restrict__ x,
    const float* __restrict__ ln1_g, const float* __restrict__ ln1_b,
    const float* __restrict__ qkv_b, const float* __restrict__ proj_b,
    const float* __restrict__ ln2_g, const float* __restrict__ ln2_b,
    const float* __restrict__ fc1_b, const float* __restrict__ fc2_b,
    const unsigned short* __restrict__ wqkv,   // [288][96] bf16
    const unsigned short* __restrict__ wproj,  // [96][96] bf16
    const unsigned short* __restrict__ wfc1,   // [384][96] bf16
    const unsigned short* __restrict__ wfc2,   // [96][384] bf16
    const unsigned short* __restrict__ bmfrag,
    float* __restrict__ out)
{
    __shared__ __align__(16) unsigned char smem[53760];
    unsigned short (*xt)[104]  = (unsigned short(*)[104])(smem);
    unsigned short (*qs)[104]  = (unsigned short(*)[104])(smem + 13312);
    unsigned short (*kss)[104] = (unsigned short(*)[104])(smem + 26624);
    unsigned short (*vs)[72]   = (unsigned short(*)[72])(smem + 39936);
    unsigned short (*m1)[104]  = (unsigned short(*)[104])(smem + 13312);
    float          (*hbuf)[101]= (float(*)[101])(smem + 26624);
    unsigned short (*xs)[104]  = xt;

    const int w = blockIdx.x, b = w >> 6, widx = w & 63;
    const int wi = widx >> 3, wj = widx & 7;
    const int tid = threadIdx.x, wave = tid >> 6, lane = tid & 63;
    const int l15 = lane & 15, lk = (lane >> 4) * 8, g4 = (lane >> 4) * 4;
    const int rb = wave & 3, half = wave >> 2;   // row-block / task-half per wave

    // ---- Phase 1: LN1 + shifted gather (roll -3,-3); 8 threads per row ----
    {
        const int n = tid >> 3, oc = tid & 7;
        if (n < 49) {
            const int p = n / 7, qq = n - 7 * p;
            int sr = wi * 7 + p + 3;   if (sr >= 56) sr -= 56;
            int scl = wj * 7 + qq + 3; if (scl >= 56) scl -= 56;
            const float* xr = x + ((size_t)b * 3136 + (size_t)(sr * 56 + scl)) * CDIM + oc * 12;
            float vals[12];
            float s = 0.f, ss2 = 0.f;
            #pragma unroll
            for (int i = 0; i < 3; ++i) {
                const float4 f = *(const float4*)(xr + i * 4);
                vals[i*4+0] = f.x; vals[i*4+1] = f.y; vals[i*4+2] = f.z; vals[i*4+3] = f.w;
                s += f.x + f.y + f.z + f.w;
                ss2 += f.x*f.x + f.y*f.y + f.z*f.z + f.w*f.w;
            }
            s += __shfl_xor(s, 1);  ss2 += __shfl_xor(ss2, 1);
            s += __shfl_xor(s, 2);  ss2 += __shfl_xor(ss2, 2);
            s += __shfl_xor(s, 4);  ss2 += __shfl_xor(ss2, 4);
            const float mean = s * (1.f / 96.f);
            const float rstd = rsqrtf(ss2 * (1.f / 96.f) - mean * mean + 1e-5f);
            #pragma unroll
            for (int v4 = 0; v4 < 3; ++v4) {
                const float4 gg = *(const float4*)(ln1_g + oc * 12 + v4 * 4);
                const float4 bb = *(const float4*)(ln1_b + oc * 12 + v4 * 4);
                u32x2 pv;
                pv.x = pkcvt((vals[v4*4+0]-mean)*rstd*gg.x + bb.x,
                             (vals[v4*4+1]-mean)*rstd*gg.y + bb.y);
                pv.y = pkcvt((vals[v4*4+2]-mean)*rstd*gg.z + bb.z,
                             (vals[v4*4+3]-mean)*rstd*gg.w + bb.w);
                *(u32x2*)&xt[n][oc * 12 + v4 * 4] = pv;
            }
        } else {
            const u32x2 z = {0u, 0u};
            #pragma unroll
            for (int v4 = 0; v4 < 3; ++v4) *(u32x2*)&xt[n][oc * 12 + v4 * 4] = z;
        }
    }
    __syncthreads();

    // ---- Phase 2: qkv projection; wave owns xt row-block rb, B-frags hoisted ----
    {
        const bf16x8 bx0 = *(const bf16x8*)&xt[rb * 16 + l15][lk];
        const bf16x8 bx1 = *(const bf16x8*)&xt[rb * 16 + l15][32 + lk];
        const bf16x8 bx2 = *(const bf16x8*)&xt[rb * 16 + l15][64 + lk];
        // Q/K swapped GEMM: 6 feat-tiles per wave
        #pragma unroll
        for (int j = 0; j < 6; ++j) {
            const int qt = half * 6 + j;             // 0..11 (feats 0..191)
            const unsigned short* wr = wqkv + (size_t)(qt * 16 + l15) * 96;
            f32x4 acc = {0.f, 0.f, 0.f, 0.f};
            __builtin_amdgcn_s_setprio(1);
            acc = __builtin_amdgcn_mfma_f32_16x16x32_bf16(*(const bf16x8*)(wr + lk),      bx0, acc, 0, 0, 0);
            acc = __builtin_amdgcn_mfma_f32_16x16x32_bf16(*(const bf16x8*)(wr + 32 + lk), bx1, acc, 0, 0, 0);
            acc = __builtin_amdgcn_mfma_f32_16x16x32_bf16(*(const bf16x8*)(wr + 64 + lk), bx2, acc, 0, 0, 0);
            __builtin_amdgcn_s_setprio(0);
            const int f0 = qt * 16 + g4;
            const float4 bias = *(const float4*)(qkv_b + f0);
            const int tok = rb * 16 + l15;
            u32x2 pw;
            if (qt < 6) {                            // Q (scale folded)
                pw.x = pkcvt((acc[0] + bias.x) * SCALE_QK, (acc[1] + bias.y) * SCALE_QK);
                pw.y = pkcvt((acc[2] + bias.z) * SCALE_QK, (acc[3] + bias.w) * SCALE_QK);
                *(u32x2*)&qs[tok][f0] = pw;
            } else {                                 // K
                pw.x = pkcvt(acc[0] + bias.x, acc[1] + bias.y);
                pw.y = pkcvt(acc[2] + bias.z, acc[3] + bias.w);
                *(u32x2*)&kss[tok][f0 - 96] = pw;
            }
        }
        // V normal GEMM: 3 vfeat-tiles per wave (A-frag == bx)
        #pragma unroll
        for (int j = 0; j < 3; ++j) {
            const int vt = half * 3 + j;             // 0..5
            const unsigned short* wr = wqkv + (size_t)(192 + vt * 16 + l15) * 96;
            f32x4 acc = {0.f, 0.f, 0.f, 0.f};
            __builtin_amdgcn_s_setprio(1);
            acc = __builtin_amdgcn_mfma_f32_16x16x32_bf16(bx0, *(const bf16x8*)(wr + lk),      acc, 0, 0, 0);
            acc = __builtin_amdgcn_mfma_f32_16x16x32_bf16(bx1, *(const bf16x8*)(wr + 32 + lk), acc, 0, 0, 0);
            acc = __builtin_amdgcn_mfma_f32_16x16x32_bf16(bx2, *(const bf16x8*)(wr + 64 + lk), acc, 0, 0, 0);
            __builtin_amdgcn_s_setprio(0);
            const float bias = qkv_b[192 + vt * 16 + l15];
            u32x2 pw;
            pw.x = pkcvt(acc[0] + bias, acc[1] + bias);
            pw.y = pkcvt(acc[2] + bias, acc[3] + bias);
            *(u32x2*)&vs[vt * 16 + l15][rb * 16 + g4] = pw;
        }
    }
    __syncthreads();

    // ---- Phase 3: swapped QK^T + register softmax + in-register P exchange + PV ----
    #pragma unroll
    for (int it = 0; it < 2; ++it) {
        const int ui = wave + 8 * it;
        if (ui < 12) {
            const int h = ui >> 2, mt = ui & 3;
            const bf16x8 bq = *(const bf16x8*)&qs[mt * 16 + l15][h * 32 + lk];
            const unsigned short* bmb = bmfrag + (size_t)(widx * 3 + h) * 4096 + mt * 256;
            f32x4 s[4];
            #pragma unroll
            for (int kt = 0; kt < 4; ++kt) {
                const bf16x8 ak = *(const bf16x8*)&kss[kt * 16 + l15][h * 32 + lk];
                const u32x2 cw = *(const u32x2*)(bmb + kt * 1024 + lane * 4);
                f32x4 c;
                c[0] = bitsf(cw.x << 16); c[1] = bitsf(cw.x & 0xffff0000u);
                c[2] = bitsf(cw.y << 16); c[3] = bitsf(cw.y & 0xffff0000u);
                __builtin_amdgcn_s_setprio(1);
                s[kt] = __builtin_amdgcn_mfma_f32_16x16x32_bf16(ak, bq, c, 0, 0, 0);
                __builtin_amdgcn_s_setprio(0);
            }
            float mx = s[0][0];
            #pragma unroll
            for (int kt = 0; kt < 4; ++kt)
                #pragma unroll
                for (int rr = 0; rr < 4; ++rr) mx = fmaxf(mx, s[kt][rr]);
            mx = fmaxf(mx, __shfl_xor(mx, 16));
            mx = fmaxf(mx, __shfl_xor(mx, 32));
            float sum = 0.f;
            #pragma unroll
            for (int kt = 0; kt < 4; ++kt)
                #pragma unroll
                for (int rr = 0; rr < 4; ++rr) {
                    const float e = __expf(s[kt][rr] - mx);
                    s[kt][rr] = e; sum += e;
                }
            sum += __shfl_xor(sum, 16);
            sum += __shfl_xor(sum, 32);
            const float inv = __fdividef(1.0f, sum);
            unsigned pk00 = pkcvt(s[0][0], s[0][1]), pk01 = pkcvt(s[0][2], s[0][3]);
            unsigned pk10 = pkcvt(s[1][0], s[1][1]), pk11 = pkcvt(s[1][2], s[1][3]);
            unsigned pk20 = pkcvt(s[2][0], s[2][1]), pk21 = pkcvt(s[2][2], s[2][3]);
            unsigned pk30 = pkcvt(s[3][0], s[3][1]), pk31 = pkcvt(s[3][2], s[3][3]);
            const int srcA = ((lane >> 4) & 1) * 32 + l15;
            const int srcB = srcA + 16;
            const bool hi = (lane & 32) != 0;
            unsigned a0, a1, a2, a3, b0, b1, b2, b3;
            a0 = __shfl(pk00, srcA); a1 = __shfl(pk01, srcA);
            a2 = __shfl(pk10, srcA); a3 = __shfl(pk11, srcA);
            b0 = __shfl(pk00, srcB); b1 = __shfl(pk01, srcB);
            b2 = __shfl(pk10, srcB); b3 = __shfl(pk11, srcB);
            const bf16x8 pb0 = mk8(hi ? a2 : a0, hi ? a3 : a1, hi ? b2 : b0, hi ? b3 : b1);
            a0 = __shfl(pk20, srcA); a1 = __shfl(pk21, srcA);
            a2 = __shfl(pk30, srcA); a3 = __shfl(pk31, srcA);
            b0 = __shfl(pk20, srcB); b1 = __shfl(pk21, srcB);
            b2 = __shfl(pk30, srcB); b3 = __shfl(pk31, srcB);
            const bf16x8 pb1 = mk8(hi ? a2 : a0, hi ? a3 : a1, hi ? b2 : b0, hi ? b3 : b1);
            f32x4 o0 = {0.f,0.f,0.f,0.f}, o1 = {0.f,0.f,0.f,0.f};
            {
                const bf16x8 v00 = *(const bf16x8*)&vs[h * 32 + l15][lk];
                const bf16x8 v01 = *(const bf16x8*)&vs[h * 32 + l15][32 + lk];
                const bf16x8 v10 = *(const bf16x8*)&vs[h * 32 + 16 + l15][lk];
                const bf16x8 v11 = *(const bf16x8*)&vs[h * 32 + 16 + l15][32 + lk];
                __builtin_amdgcn_s_setprio(1);
                o0 = __builtin_amdgcn_mfma_f32_16x16x32_bf16(v00, pb0, o0, 0, 0, 0);
                o0 = __builtin_amdgcn_mfma_f32_16x16x32_bf16(v01, pb1, o0, 0, 0, 0);
                o1 = __builtin_amdgcn_mfma_f32_16x16x32_bf16(v10, pb0, o1, 0, 0, 0);
                o1 = __builtin_amdgcn_mfma_f32_16x16x32_bf16(v11, pb1, o1, 0, 0, 0);
                __builtin_amdgcn_s_setprio(0);
            }
            u32x2 ow;
            ow.x = pkcvt(o0[0] * inv, o0[1] * inv);
            ow.y = pkcvt(o0[2] * inv, o0[3] * inv);
            *(u32x2*)&xt[mt * 16 + l15][h * 32 + g4] = ow;
            ow.x = pkcvt(o1[0] * inv, o1[1] * inv);
            ow.y = pkcvt(o1[2] * inv, o1[3] * inv);
            *(u32x2*)&xt[mt * 16 + l15][h * 32 + 16 + g4] = ow;
        }
    }
    __syncthreads();

    // ---- Phase 4: proj + x-residual -> hbuf (fp32); A-frags hoisted; pad rows -> 0 ----
    {
        const bf16x8 a0 = *(const bf16x8*)&xt[rb * 16 + l15][lk];
        const bf16x8 a1 = *(const bf16x8*)&xt[rb * 16 + l15][32 + lk];
        const bf16x8 a2 = *(const bf16x8*)&xt[rb * 16 + l15][64 + lk];
        #pragma unroll
        for (int j = 0; j < 3; ++j) {
            const int nt = half * 3 + j;
            const unsigned short* wr = wproj + (size_t)(nt * 16 + l15) * 96;
            f32x4 acc = {0.f, 0.f, 0.f, 0.f};
            __builtin_amdgcn_s_setprio(1);
            acc = __builtin_amdgcn_mfma_f32_16x16x32_bf16(a0, *(const bf16x8*)(wr + lk),      acc, 0, 0, 0);
            acc = __builtin_amdgcn_mfma_f32_16x16x32_bf16(a1, *(const bf16x8*)(wr + 32 + lk), acc, 0, 0, 0);
            acc = __builtin_amdgcn_mfma_f32_16x16x32_bf16(a2, *(const bf16x8*)(wr + 64 + lk), acc, 0, 0, 0);
            __builtin_amdgcn_s_setprio(0);
            const int colf = nt * 16 + l15;
            const float pb = proj_b[colf];
            #pragma unroll
            for (int rr = 0; rr < 4; ++rr) {
                const int n = rb * 16 + g4 + rr;
                if (n < 49) {
                    const int p = n / 7, q = n - 7 * p;
                    int sr = wi * 7 + p + 3;  if (sr >= 56) sr -= 56;
                    int scl = wj * 7 + q + 3; if (scl >= 56) scl -= 56;
                    const size_t base = ((size_t)b * 3136 + (size_t)(sr * 56 + scl)) * CDIM + colf;
                    hbuf[n][colf] = acc[rr] + pb + x[base];
                } else {
                    hbuf[n][colf] = 0.f;
                }
            }
        }
    }
    __syncthreads();

    // ---- Phase 5: LN2 hbuf -> xs (bf16) ----
    {
        const int n = tid >> 3, oc = tid & 7;
        float vals[12];
        float s = 0.f, ss2 = 0.f;
        #pragma unroll
        for (int i = 0; i < 3; ++i) {
            const float4 f = *(const float4*)&hbuf[n][oc * 12 + i * 4];
            vals[i*4+0] = f.x; vals[i*4+1] = f.y; vals[i*4+2] = f.z; vals[i*4+3] = f.w;
            s += f.x + f.y + f.z + f.w;
            ss2 += f.x*f.x + f.y*f.y + f.z*f.z + f.w*f.w;
        }
        s += __shfl_xor(s, 1);  ss2 += __shfl_xor(ss2, 1);
        s += __shfl_xor(s, 2);  ss2 += __shfl_xor(ss2, 2);
        s += __shfl_xor(s, 4);  ss2 += __shfl_xor(ss2, 4);
        const float mean = s * (1.f / 96.f);
        const float rstd = rsqrtf(ss2 * (1.f / 96.f) - mean * mean + 1e-5f);
        #pragma unroll
        for (int v4 = 0; v4 < 3; ++v4) {
            const float4 gg = *(const float4*)(ln2_g + oc * 12 + v4 * 4);
            const float4 bb = *(const float4*)(ln2_b + oc * 12 + v4 * 4);
            u32x2 pv;
            pv.x = pkcvt((vals[v4*4+0]-mean)*rstd*gg.x + bb.x,
                         (vals[v4*4+1]-mean)*rstd*gg.y + bb.y);
            pv.y = pkcvt((vals[v4*4+2]-mean)*rstd*gg.z + bb.z,
                         (vals[v4*4+3]-mean)*rstd*gg.w + bb.w);
            *(u32x2*)&xs[n][oc * 12 + v4 * 4] = pv;
        }
    }
    __syncthreads();

    // ---- Phase 6: MLP, 4 hidden chunks of 96; m1 in LDS (qs region); fc2 acc in regs ----
    {
        const bf16x8 mbx0 = *(const bf16x8*)&xs[rb * 16 + l15][lk];
        const bf16x8 mbx1 = *(const bf16x8*)&xs[rb * 16 + l15][32 + lk];
        const bf16x8 mbx2 = *(const bf16x8*)&xs[rb * 16 + l15][64 + lk];
        f32x4 facc[3] = {{0.f,0.f,0.f,0.f},{0.f,0.f,0.f,0.f},{0.f,0.f,0.f,0.f}};
        #pragma unroll
        for (int c = 0; c < 4; ++c) {
            const int hb = c * 96;
            // fc1 chunk + tanh-GELU, swapped GEMM C[hid][tok] -> m1[tok][hid_local]
            #pragma unroll
            for (int i = 0; i < 3; ++i) {
                const int ft = half + 2 * i;         // 0..5 local hidden tile
                const unsigned short* wr = wfc1 + (size_t)(hb + ft * 16 + l15) * 96;
                f32x4 acc = {0.f, 0.f, 0.f, 0.f};
                __builtin_amdgcn_s_setprio(1);
                acc = __builtin_amdgcn_mfma_f32_16x16x32_bf16(*(const bf16x8*)(wr + lk),      mbx0, acc, 0, 0, 0);
                acc = __builtin_amdgcn_mfma_f32_16x16x32_bf16(*(const bf16x8*)(wr + 32 + lk), mbx1, acc, 0, 0, 0);
                acc = __builtin_amdgcn_mfma_f32_16x16x32_bf16(*(const bf16x8*)(wr + 64 + lk), mbx2, acc, 0, 0, 0);
                __builtin_amdgcn_s_setprio(0);
                const int f0 = ft * 16 + g4;
                const float4 bias = *(const float4*)(fc1_b + hb + f0);
                const float* bp = &bias.x;
                float g[4];
                #pragma unroll
                for (int rr = 0; rr < 4; ++rr) {
                    const float u = acc[rr] + bp[rr];
                    const float u2 = u * u;
                    const float n2y = u * (-1.5957691216f - 0.0713548162f * u2);
                    g[rr] = __fdividef(u, 1.f + __expf(n2y));
                }
                u32x2 pw;
                pw.x = pkcvt(g[0], g[1]);
                pw.y = pkcvt(g[2], g[3]);
                *(u32x2*)&m1[rb * 16 + l15][f0] = pw;
            }
            __syncthreads();
            // fc2 partial: C2[cout][tok], K=96 (3 MFMA), acc across chunks
            #pragma unroll
            for (int i = 0; i < 3; ++i) {
                const int ct = half + 2 * i;         // 0..5 cout tile
                const unsigned short* wr = wfc2 + (size_t)(ct * 16 + l15) * 384 + hb;
                __builtin_amdgcn_s_setprio(1);
                facc[i] = __builtin_amdgcn_mfma_f32_16x16x32_bf16(
                    *(const bf16x8*)(wr + lk), *(const bf16x8*)&m1[rb * 16 + l15][lk], facc[i], 0, 0, 0);
                facc[i] = __builtin_amdgcn_mfma_f32_16x16x32_bf16(
                    *(const bf16x8*)(wr + 32 + lk), *(const bf16x8*)&m1[rb * 16 + l15][32 + lk], facc[i], 0, 0, 0);
                facc[i] = __builtin_amdgcn_mfma_f32_16x16x32_bf16(
                    *(const bf16x8*)(wr + 64 + lk), *(const bf16x8*)&m1[rb * 16 + l15][64 + lk], facc[i], 0, 0, 0);
                __builtin_amdgcn_s_setprio(0);
            }
            if (c < 3) __syncthreads();
        }

        // ---- Phase 7: out = h + fc2 + b2, float4 stores (unshift scatter) ----
        const int n = rb * 16 + l15;
        if (n < 49) {
            const int p = n / 7, q = n - 7 * p;
            int sr = wi * 7 + p + 3;  if (sr >= 56) sr -= 56;
            int scl = wj * 7 + q + 3; if (scl >= 56) scl -= 56;
            float* ob = out + ((size_t)b * 3136 + (size_t)(sr * 56 + scl)) * CDIM;
            #pragma unroll
            for (int i = 0; i < 3; ++i) {
                const int cb = (half + 2 * i) * 16 + g4;
                const float4 hv  = *(const float4*)&hbuf[n][cb];
                const float4 b2v = *(const float4*)(fc2_b + cb);
                float4 o4;
                o4.x = hv.x + facc[i][0] + b2v.x;
                o4.y = hv.y + facc[i][1] + b2v.y;
                o4.z = hv.z + facc[i][2] + b2v.z;
                o4.w = hv.w + facc[i][3] + b2v.w;
                *(float4*)(ob + cb) = o4;
            }
        }
    }
}

extern "C" void kernel_launch(void* const* d_in, const int* in_sizes, int n_in,
                              void* d_out, int out_size, void* d_ws, size_t ws_size,
                              hipStream_t stream) {
    (void)n_in; (void)out_size; (void)ws_size;
    const float* x        = (const float*)d_in[0];
    const float* attn_msk = (const float*)d_in[1];
    const float* ln1_g    = (const float*)d_in[2];
    const float* ln1_b    = (const float*)d_in[3];
    const float* qkv_w    = (const float*)d_in[4];
    const float* qkv_b    = (const float*)d_in[5];
    const float* rel_tab  = (const float*)d_in[6];
    const int*   rel_idx  = (const int*)d_in[7];
    const float* proj_w   = (const float*)d_in[8];
    const float* proj_b   = (const float*)d_in[9];
    const float* ln2_g    = (const float*)d_in[10];
    const float* ln2_b    = (const float*)d_in[11];
    const float* fc1_w    = (const float*)d_in[12];
    const float* fc1_b    = (const float*)d_in[13];
    const float* fc2_w    = (const float*)d_in[14];
    const float* fc2_b    = (const float*)d_in[15];
    float* out = (float*)d_out;
    unsigned short* wsb = (unsigned short*)d_ws;
    unsigned short* bmf = wsb + 110592;

    const int B = in_sizes[0] / (3136 * 96);   // 64

    conv_w_kernel<<<(110592 + 255) / 256, 256, 0, stream>>>(qkv_w, proj_w, fc1_w, fc2_w, wsb);
    build_bmfrag_kernel<<<196608 / 256, 256, 0, stream>>>(attn_msk, rel_tab, rel_idx, bmf);

    swin_fused<<<B * 64, 512, 0, stream>>>(
        x, ln1_g, ln1_b, qkv_b, proj_b, ln2_g, ln2_b, fc1_b, fc2_b,
        wsb, wsb + 27648, wsb + 36864, wsb + 73728, bmf, out);
}

// Round 10
// 325.950 us; speedup vs baseline: 1.2197x; 1.0520x over previous
//
#include <hip/hip_runtime.h>
#include <math.h>

// Swin block, fused bf16-MFMA kernel. R10: Q in registers (no qs buffer),
// LDS 40448 B -> 4 blocks/CU, no setprio.
// B=64, H=W=56, C=96, WS=7, SS=3, NH=3, HD=32, N=49 (padded 64), nW=64.

#define CDIM 96
#define SCALE_QK 0.17677669529663687f  // 32^-0.5

typedef __attribute__((ext_vector_type(8))) short bf16x8;
typedef __attribute__((ext_vector_type(4))) float f32x4;
typedef __attribute__((ext_vector_type(2))) unsigned int u32x2;
typedef __attribute__((ext_vector_type(4))) unsigned int u32x4;

__device__ inline unsigned short f2b(float f) {
    union { float f; unsigned u; } v; v.f = f;
    unsigned r = v.u + 0x7FFF + ((v.u >> 16) & 1);   // RNE
    return (unsigned short)(r >> 16);
}
__device__ inline unsigned pkcvt(float a, float b) {   // low16=bf16(a), high16=bf16(b)
    unsigned d;
    asm("v_cvt_pk_bf16_f32 %0, %1, %2" : "=v"(d) : "v"(a), "v"(b));
    return d;
}
__device__ inline float bitsf(unsigned u) {
    union { unsigned u; float f; } v; v.u = u; return v.f;
}
__device__ inline bf16x8 mk8(unsigned d0, unsigned d1, unsigned d2, unsigned d3) {
    union { u32x4 u; bf16x8 h; } v;
    v.u = (u32x4){d0, d1, d2, d3};
    return v.h;
}

// ---------------- Kernel 0a: weights fp32 -> bf16 ----------------
__global__ __launch_bounds__(256) void conv_w_kernel(
    const float* __restrict__ qkv_w, const float* __restrict__ proj_w,
    const float* __restrict__ fc1_w, const float* __restrict__ fc2_w,
    unsigned short* __restrict__ ws)
{
    const int i = blockIdx.x * 256 + threadIdx.x;
    if (i < 27648)       ws[i] = f2b(qkv_w[i]);
    else if (i < 36864)  ws[i] = f2b(proj_w[i - 27648]);
    else if (i < 73728)  ws[i] = f2b(fc1_w[i - 36864]);
    else if (i < 110592) ws[i] = f2b(fc2_w[i - 73728]);
}

// ---------------- Kernel 0b: bias+mask in MFMA C-fragment layout, bf16 ----------------
__global__ __launch_bounds__(256) void build_bmfrag_kernel(
    const float* __restrict__ attn_mask, const float* __restrict__ rel_bias_table,
    const int* __restrict__ rel_index, unsigned short* __restrict__ bmf)
{
    const int i = blockIdx.x * 256 + threadIdx.x;   // 196608 total
    const int lane = i & 63;
    const int mt = (i >> 6) & 3;
    const int kt = (i >> 8) & 3;
    const int t3 = i >> 10;                          // widx*3 + h
    const int h = t3 % 3, widx = t3 / 3;
    const int q = mt * 16 + (lane & 15);
    const int kb = kt * 16 + (lane >> 4) * 4;
    float vv[4];
    #pragma unroll
    for (int rr = 0; rr < 4; ++rr) {
        const int k = kb + rr;
        float val = -1.0e30f;
        if (q < 49 && k < 49) {
            const int idx = q * 49 + k;
            val = rel_bias_table[rel_index[idx] * 3 + h] + attn_mask[widx * 2401 + idx];
        }
        vv[rr] = val;
    }
    u32x2 pw;
    pw.x = (unsigned)f2b(vv[0]) | ((unsigned)f2b(vv[1]) << 16);
    pw.y = (unsigned)f2b(vv[2]) | ((unsigned)f2b(vv[3]) << 16);
    *(u32x2*)(bmf + (size_t)i * 4) = pw;
}

// ---------------- Fused kernel ----------------
// LDS (40448 B): xt [64][104]u16 @0 | kss [64][104] @13312 | vs [96][72] @26624.
// Aliases: hbuf [64][101]f32 @13312 (over kss+vs, after attn);
//          m1 [64][104]u16 @0 (over xt/xs, after P6 hoist).
__global__ __launch_bounds__(512, 8) void swin_fused(
    const float* __restrict__ x,
    const float* __restrict__ ln1_g, const float* __restrict__ ln1_b,
    const float* __restrict__ qkv_b, const float* __restrict__ proj_b,
    const float* __restrict__ ln2_g, const float* __restrict__ ln2_b,
    const float* __restrict__ fc1_b, const float* __restrict__ fc2_b,
    const unsigned short* __restrict__ wqkv,   // [288][96] bf16
    const unsigned short* __restrict__ wproj,  // [96][96] bf16
    const unsigned short* __restrict__ wfc1,   // [384][96] bf16
    const unsigned short* __restrict__ wfc2,   // [96][384] bf16
    const unsigned short* __restrict__ bmfrag,
    float* __restrict__ out)
{
    __shared__ __align__(16) unsigned char smem[40448];
    unsigned short (*xt)[104]  = (unsigned short(*)[104])(smem);
    unsigned short (*kss)[104] = (unsigned short(*)[104])(smem + 13312);
    unsigned short (*vs)[72]   = (unsigned short(*)[72])(smem + 26624);
    unsigned short (*m1)[104]  = (unsigned short(*)[104])(smem);        // alias xt/xs
    float          (*hbuf)[101]= (float(*)[101])(smem + 13312);         // alias kss+vs
    unsigned short (*xs)[104]  = xt;

    const int w = blockIdx.x, b = w >> 6, widx = w & 63;
    const int wi = widx >> 3, wj = widx & 7;
    const int tid = threadIdx.x, wave = tid >> 6, lane = tid & 63;
    const int l15 = lane & 15, lk = (lane >> 4) * 8, g4 = (lane >> 4) * 4;
    const int rb = wave & 3, half = wave >> 2;   // row-block / task-half per wave
    const int srcA = ((lane >> 4) & 1) * 32 + l15;
    const int srcB = srcA + 16;
    const bool hi = (lane & 32) != 0;

    // ---- Phase 1: LN1 + shifted gather (roll -3,-3); 8 threads per row ----
    {
        const int n = tid >> 3, oc = tid & 7;
        if (n < 49) {
            const int p = n / 7, qq = n - 7 * p;
            int sr = wi * 7 + p + 3;   if (sr >= 56) sr -= 56;
            int scl = wj * 7 + qq + 3; if (scl >= 56) scl -= 56;
            const float* xr = x + ((size_t)b * 3136 + (size_t)(sr * 56 + scl)) * CDIM + oc * 12;
            float vals[12];
            float s = 0.f, ss2 = 0.f;
            #pragma unroll
            for (int i = 0; i < 3; ++i) {
                const float4 f = *(const float4*)(xr + i * 4);
                vals[i*4+0] = f.x; vals[i*4+1] = f.y; vals[i*4+2] = f.z; vals[i*4+3] = f.w;
                s += f.x + f.y + f.z + f.w;
                ss2 += f.x*f.x + f.y*f.y + f.z*f.z + f.w*f.w;
            }
            s += __shfl_xor(s, 1);  ss2 += __shfl_xor(ss2, 1);
            s += __shfl_xor(s, 2);  ss2 += __shfl_xor(ss2, 2);
            s += __shfl_xor(s, 4);  ss2 += __shfl_xor(ss2, 4);
            const float mean = s * (1.f / 96.f);
            const float rstd = rsqrtf(ss2 * (1.f / 96.f) - mean * mean + 1e-5f);
            #pragma unroll
            for (int v4 = 0; v4 < 3; ++v4) {
                const float4 gg = *(const float4*)(ln1_g + oc * 12 + v4 * 4);
                const float4 bb = *(const float4*)(ln1_b + oc * 12 + v4 * 4);
                u32x2 pv;
                pv.x = pkcvt((vals[v4*4+0]-mean)*rstd*gg.x + bb.x,
                             (vals[v4*4+1]-mean)*rstd*gg.y + bb.y);
                pv.y = pkcvt((vals[v4*4+2]-mean)*rstd*gg.z + bb.z,
                             (vals[v4*4+3]-mean)*rstd*gg.w + bb.w);
                *(u32x2*)&xt[n][oc * 12 + v4 * 4] = pv;
            }
        } else {
            const u32x2 z = {0u, 0u};
            #pragma unroll
            for (int v4 = 0; v4 < 3; ++v4) *(u32x2*)&xt[n][oc * 12 + v4 * 4] = z;
        }
    }
    __syncthreads();

    // ---- Phase 2: qkv projection. K,V -> LDS; Q -> registers (C->A frag exchange) ----
    bf16x8 bq0 = {}, bq1 = {};
    {
        const bf16x8 bx0 = *(const bf16x8*)&xt[rb * 16 + l15][lk];
        const bf16x8 bx1 = *(const bf16x8*)&xt[rb * 16 + l15][32 + lk];
        const bf16x8 bx2 = *(const bf16x8*)&xt[rb * 16 + l15][64 + lk];
        // K swapped GEMM: feat-tiles 6..11 (feats 96..191), 3 per wave, token-block rb
        #pragma unroll
        for (int j = 0; j < 3; ++j) {
            const int qt = 6 + half * 3 + j;
            const unsigned short* wr = wqkv + (size_t)(qt * 16 + l15) * 96;
            f32x4 acc = {0.f, 0.f, 0.f, 0.f};
            acc = __builtin_amdgcn_mfma_f32_16x16x32_bf16(*(const bf16x8*)(wr + lk),      bx0, acc, 0, 0, 0);
            acc = __builtin_amdgcn_mfma_f32_16x16x32_bf16(*(const bf16x8*)(wr + 32 + lk), bx1, acc, 0, 0, 0);
            acc = __builtin_amdgcn_mfma_f32_16x16x32_bf16(*(const bf16x8*)(wr + 64 + lk), bx2, acc, 0, 0, 0);
            const int f0 = qt * 16 + g4;
            const float4 bias = *(const float4*)(qkv_b + f0);
            u32x2 pw;
            pw.x = pkcvt(acc[0] + bias.x, acc[1] + bias.y);
            pw.y = pkcvt(acc[2] + bias.z, acc[3] + bias.w);
            *(u32x2*)&kss[rb * 16 + l15][f0 - 96] = pw;
        }
        // V normal GEMM: 3 vfeat-tiles per wave, token rows rb
        #pragma unroll
        for (int j = 0; j < 3; ++j) {
            const int vt = half * 3 + j;             // 0..5
            const unsigned short* wr = wqkv + (size_t)(192 + vt * 16 + l15) * 96;
            f32x4 acc = {0.f, 0.f, 0.f, 0.f};
            acc = __builtin_amdgcn_mfma_f32_16x16x32_bf16(bx0, *(const bf16x8*)(wr + lk),      acc, 0, 0, 0);
            acc = __builtin_amdgcn_mfma_f32_16x16x32_bf16(bx1, *(const bf16x8*)(wr + 32 + lk), acc, 0, 0, 0);
            acc = __builtin_amdgcn_mfma_f32_16x16x32_bf16(bx2, *(const bf16x8*)(wr + 64 + lk), acc, 0, 0, 0);
            const float bias = qkv_b[192 + vt * 16 + l15];
            u32x2 pw;
            pw.x = pkcvt(acc[0] + bias, acc[1] + bias);
            pw.y = pkcvt(acc[2] + bias, acc[3] + bias);
            *(u32x2*)&vs[vt * 16 + l15][rb * 16 + g4] = pw;
        }
        // Q swapped GEMM for this wave's P3 units (h, mt=rb); exchange C->A frag in regs
        #pragma unroll
        for (int it = 0; it < 2; ++it) {
            const int ui = wave + 8 * it;
            if (ui < 12) {
                const int h = ui >> 2;
                const unsigned short* wr0 = wqkv + (size_t)(h * 32 + l15) * 96;
                const unsigned short* wr1 = wqkv + (size_t)(h * 32 + 16 + l15) * 96;
                f32x4 a0v = {0.f,0.f,0.f,0.f}, a1v = {0.f,0.f,0.f,0.f};
                a0v = __builtin_amdgcn_mfma_f32_16x16x32_bf16(*(const bf16x8*)(wr0 + lk),      bx0, a0v, 0, 0, 0);
                a0v = __builtin_amdgcn_mfma_f32_16x16x32_bf16(*(const bf16x8*)(wr0 + 32 + lk), bx1, a0v, 0, 0, 0);
                a0v = __builtin_amdgcn_mfma_f32_16x16x32_bf16(*(const bf16x8*)(wr0 + 64 + lk), bx2, a0v, 0, 0, 0);
                a1v = __builtin_amdgcn_mfma_f32_16x16x32_bf16(*(const bf16x8*)(wr1 + lk),      bx0, a1v, 0, 0, 0);
                a1v = __builtin_amdgcn_mfma_f32_16x16x32_bf16(*(const bf16x8*)(wr1 + 32 + lk), bx1, a1v, 0, 0, 0);
                a1v = __builtin_amdgcn_mfma_f32_16x16x32_bf16(*(const bf16x8*)(wr1 + 64 + lk), bx2, a1v, 0, 0, 0);
                const float4 qb0 = *(const float4*)(qkv_b + h * 32 + g4);
                const float4 qb1 = *(const float4*)(qkv_b + h * 32 + 16 + g4);
                const unsigned pk00 = pkcvt((a0v[0] + qb0.x) * SCALE_QK, (a0v[1] + qb0.y) * SCALE_QK);
                const unsigned pk01 = pkcvt((a0v[2] + qb0.z) * SCALE_QK, (a0v[3] + qb0.w) * SCALE_QK);
                const unsigned pk10 = pkcvt((a1v[0] + qb1.x) * SCALE_QK, (a1v[1] + qb1.y) * SCALE_QK);
                const unsigned pk11 = pkcvt((a1v[2] + qb1.z) * SCALE_QK, (a1v[3] + qb1.w) * SCALE_QK);
                const unsigned aa0 = __shfl(pk00, srcA), aa1 = __shfl(pk01, srcA);
                const unsigned aa2 = __shfl(pk10, srcA), aa3 = __shfl(pk11, srcA);
                const unsigned bb0 = __shfl(pk00, srcB), bb1 = __shfl(pk01, srcB);
                const unsigned bb2 = __shfl(pk10, srcB), bb3 = __shfl(pk11, srcB);
                const bf16x8 r = mk8(hi ? aa2 : aa0, hi ? aa3 : aa1, hi ? bb2 : bb0, hi ? bb3 : bb1);
                if (it == 0) bq0 = r; else bq1 = r;
            }
        }
    }
    __syncthreads();

    // ---- Phase 3: swapped QK^T + register softmax + in-register P exchange + PV ----
    #pragma unroll
    for (int it = 0; it < 2; ++it) {
        const int ui = wave + 8 * it;
        if (ui < 12) {
            const int h = ui >> 2, mt = ui & 3;      // mt == rb
            const bf16x8 bq = (it == 0) ? bq0 : bq1;
            const unsigned short* bmb = bmfrag + (size_t)(widx * 3 + h) * 4096 + mt * 256;
            f32x4 s[4];
            #pragma unroll
            for (int kt = 0; kt < 4; ++kt) {
                const bf16x8 ak = *(const bf16x8*)&kss[kt * 16 + l15][h * 32 + lk];
                const u32x2 cw = *(const u32x2*)(bmb + kt * 1024 + lane * 4);
                f32x4 c;
                c[0] = bitsf(cw.x << 16); c[1] = bitsf(cw.x & 0xffff0000u);
                c[2] = bitsf(cw.y << 16); c[3] = bitsf(cw.y & 0xffff0000u);
                s[kt] = __builtin_amdgcn_mfma_f32_16x16x32_bf16(ak, bq, c, 0, 0, 0);
            }
            float mx = s[0][0];
            #pragma unroll
            for (int kt = 0; kt < 4; ++kt)
                #pragma unroll
                for (int rr = 0; rr < 4; ++rr) mx = fmaxf(mx, s[kt][rr]);
            mx = fmaxf(mx, __shfl_xor(mx, 16));
            mx = fmaxf(mx, __shfl_xor(mx, 32));
            float sum = 0.f;
            #pragma unroll
            for (int kt = 0; kt < 4; ++kt)
                #pragma unroll
                for (int rr = 0; rr < 4; ++rr) {
                    const float e = __expf(s[kt][rr] - mx);
                    s[kt][rr] = e; sum += e;
                }
            sum += __shfl_xor(sum, 16);
            sum += __shfl_xor(sum, 32);
            const float inv = __fdividef(1.0f, sum);
            unsigned pk00 = pkcvt(s[0][0], s[0][1]), pk01 = pkcvt(s[0][2], s[0][3]);
            unsigned pk10 = pkcvt(s[1][0], s[1][1]), pk11 = pkcvt(s[1][2], s[1][3]);
            unsigned pk20 = pkcvt(s[2][0], s[2][1]), pk21 = pkcvt(s[2][2], s[2][3]);
            unsigned pk30 = pkcvt(s[3][0], s[3][1]), pk31 = pkcvt(s[3][2], s[3][3]);
            unsigned a0, a1, a2, a3, b0, b1, b2, b3;
            a0 = __shfl(pk00, srcA); a1 = __shfl(pk01, srcA);
            a2 = __shfl(pk10, srcA); a3 = __shfl(pk11, srcA);
            b0 = __shfl(pk00, srcB); b1 = __shfl(pk01, srcB);
            b2 = __shfl(pk10, srcB); b3 = __shfl(pk11, srcB);
            const bf16x8 pb0 = mk8(hi ? a2 : a0, hi ? a3 : a1, hi ? b2 : b0, hi ? b3 : b1);
            a0 = __shfl(pk20, srcA); a1 = __shfl(pk21, srcA);
            a2 = __shfl(pk30, srcA); a3 = __shfl(pk31, srcA);
            b0 = __shfl(pk20, srcB); b1 = __shfl(pk21, srcB);
            b2 = __shfl(pk30, srcB); b3 = __shfl(pk31, srcB);
            const bf16x8 pb1 = mk8(hi ? a2 : a0, hi ? a3 : a1, hi ? b2 : b0, hi ? b3 : b1);
            f32x4 o0 = {0.f,0.f,0.f,0.f}, o1 = {0.f,0.f,0.f,0.f};
            {
                const bf16x8 v00 = *(const bf16x8*)&vs[h * 32 + l15][lk];
                const bf16x8 v01 = *(const bf16x8*)&vs[h * 32 + l15][32 + lk];
                const bf16x8 v10 = *(const bf16x8*)&vs[h * 32 + 16 + l15][lk];
                const bf16x8 v11 = *(const bf16x8*)&vs[h * 32 + 16 + l15][32 + lk];
                o0 = __builtin_amdgcn_mfma_f32_16x16x32_bf16(v00, pb0, o0, 0, 0, 0);
                o0 = __builtin_amdgcn_mfma_f32_16x16x32_bf16(v01, pb1, o0, 0, 0, 0);
                o1 = __builtin_amdgcn_mfma_f32_16x16x32_bf16(v10, pb0, o1, 0, 0, 0);
                o1 = __builtin_amdgcn_mfma_f32_16x16x32_bf16(v11, pb1, o1, 0, 0, 0);
            }
            u32x2 ow;
            ow.x = pkcvt(o0[0] * inv, o0[1] * inv);
            ow.y = pkcvt(o0[2] * inv, o0[3] * inv);
            *(u32x2*)&xt[mt * 16 + l15][h * 32 + g4] = ow;
            ow.x = pkcvt(o1[0] * inv, o1[1] * inv);
            ow.y = pkcvt(o1[2] * inv, o1[3] * inv);
            *(u32x2*)&xt[mt * 16 + l15][h * 32 + 16 + g4] = ow;
        }
    }
    __syncthreads();

    // ---- Phase 4: proj + x-residual -> hbuf (fp32); A-frags hoisted; pad rows -> 0 ----
    {
        const bf16x8 a0 = *(const bf16x8*)&xt[rb * 16 + l15][lk];
        const bf16x8 a1 = *(const bf16x8*)&xt[rb * 16 + l15][32 + lk];
        const bf16x8 a2 = *(const bf16x8*)&xt[rb * 16 + l15][64 + lk];
        __syncthreads();   // all P4 A-frag reads of xt done before any hbuf write (hbuf aliases kss/vs, xt safe; barrier orders vs P3 stragglers on other SIMDs reading kss/vs)
        #pragma unroll
        for (int j = 0; j < 3; ++j) {
            const int nt = half * 3 + j;
            const unsigned short* wr = wproj + (size_t)(nt * 16 + l15) * 96;
            f32x4 acc = {0.f, 0.f, 0.f, 0.f};
            acc = __builtin_amdgcn_mfma_f32_16x16x32_bf16(a0, *(const bf16x8*)(wr + lk),      acc, 0, 0, 0);
            acc = __builtin_amdgcn_mfma_f32_16x16x32_bf16(a1, *(const bf16x8*)(wr + 32 + lk), acc, 0, 0, 0);
            acc = __builtin_amdgcn_mfma_f32_16x16x32_bf16(a2, *(const bf16x8*)(wr + 64 + lk), acc, 0, 0, 0);
            const int colf = nt * 16 + l15;
            const float pb = proj_b[colf];
            #pragma unroll
            for (int rr = 0; rr < 4; ++rr) {
                const int n = rb * 16 + g4 + rr;
                if (n < 49) {
                    const int p = n / 7, q = n - 7 * p;
                    int sr = wi * 7 + p + 3;  if (sr >= 56) sr -= 56;
                    int scl = wj * 7 + q + 3; if (scl >= 56) scl -= 56;
                    const size_t base = ((size_t)b * 3136 + (size_t)(sr * 56 + scl)) * CDIM + colf;
                    hbuf[n][colf] = acc[rr] + pb + x[base];
                } else {
                    hbuf[n][colf] = 0.f;
                }
            }
        }
    }
    __syncthreads();

    // ---- Phase 5: LN2 hbuf -> xs (bf16) ----
    {
        const int n = tid >> 3, oc = tid & 7;
        float vals[12];
        float s = 0.f, ss2 = 0.f;
        #pragma unroll
        for (int i = 0; i < 3; ++i) {
            const float4 f = *(const float4*)&hbuf[n][oc * 12 + i * 4];
            vals[i*4+0] = f.x; vals[i*4+1] = f.y; vals[i*4+2] = f.z; vals[i*4+3] = f.w;
            s += f.x + f.y + f.z + f.w;
            ss2 += f.x*f.x + f.y*f.y + f.z*f.z + f.w*f.w;
        }
        s += __shfl_xor(s, 1);  ss2 += __shfl_xor(ss2, 1);
        s += __shfl_xor(s, 2);  ss2 += __shfl_xor(ss2, 2);
        s += __shfl_xor(s, 4);  ss2 += __shfl_xor(ss2, 4);
        const float mean = s * (1.f / 96.f);
        const float rstd = rsqrtf(ss2 * (1.f / 96.f) - mean * mean + 1e-5f);
        #pragma unroll
        for (int v4 = 0; v4 < 3; ++v4) {
            const float4 gg = *(const float4*)(ln2_g + oc * 12 + v4 * 4);
            const float4 bb = *(const float4*)(ln2_b + oc * 12 + v4 * 4);
            u32x2 pv;
            pv.x = pkcvt((vals[v4*4+0]-mean)*rstd*gg.x + bb.x,
                         (vals[v4*4+1]-mean)*rstd*gg.y + bb.y);
            pv.y = pkcvt((vals[v4*4+2]-mean)*rstd*gg.z + bb.z,
                         (vals[v4*4+3]-mean)*rstd*gg.w + bb.w);
            *(u32x2*)&xs[n][oc * 12 + v4 * 4] = pv;
        }
    }
    __syncthreads();

    // ---- Phase 6: MLP, 4 hidden chunks of 96; m1 aliases xs (hoist first); fc2 acc in regs ----
    {
        const bf16x8 mbx0 = *(const bf16x8*)&xs[rb * 16 + l15][lk];
        const bf16x8 mbx1 = *(const bf16x8*)&xs[rb * 16 + l15][32 + lk];
        const bf16x8 mbx2 = *(const bf16x8*)&xs[rb * 16 + l15][64 + lk];
        __syncthreads();   // all xs hoists complete before m1 overwrites the region
        f32x4 facc[3] = {{0.f,0.f,0.f,0.f},{0.f,0.f,0.f,0.f},{0.f,0.f,0.f,0.f}};
        #pragma unroll
        for (int c = 0; c < 4; ++c) {
            const int hb = c * 96;
            // fc1 chunk + tanh-GELU, swapped GEMM C[hid][tok] -> m1[tok][hid_local]
            #pragma unroll
            for (int i = 0; i < 3; ++i) {
                const int ft = half + 2 * i;         // 0..5 local hidden tile
                const unsigned short* wr = wfc1 + (size_t)(hb + ft * 16 + l15) * 96;
                f32x4 acc = {0.f, 0.f, 0.f, 0.f};
                acc = __builtin_amdgcn_mfma_f32_16x16x32_bf16(*(const bf16x8*)(wr + lk),      mbx0, acc, 0, 0, 0);
                acc = __builtin_amdgcn_mfma_f32_16x16x32_bf16(*(const bf16x8*)(wr + 32 + lk), mbx1, acc, 0, 0, 0);
                acc = __builtin_amdgcn_mfma_f32_16x16x32_bf16(*(const bf16x8*)(wr + 64 + lk), mbx2, acc, 0, 0, 0);
                const int f0 = ft * 16 + g4;
                const float4 bias = *(const float4*)(fc1_b + hb + f0);
                const float* bp = &bias.x;
                float g[4];
                #pragma unroll
                for (int rr = 0; rr < 4; ++rr) {
                    const float u = acc[rr] + bp[rr];
                    const float u2 = u * u;
                    const float n2y = u * (-1.5957691216f - 0.0713548162f * u2);
                    g[rr] = __fdividef(u, 1.f + __expf(n2y));
                }
                u32x2 pw;
                pw.x = pkcvt(g[0], g[1]);
                pw.y = pkcvt(g[2], g[3]);
                *(u32x2*)&m1[rb * 16 + l15][f0] = pw;
            }
            __syncthreads();
            // fc2 partial: C2[cout][tok], K=96 (3 MFMA), acc across chunks
            #pragma unroll
            for (int i = 0; i < 3; ++i) {
                const int ct = half + 2 * i;         // 0..5 cout tile
                const unsigned short* wr = wfc2 + (size_t)(ct * 16 + l15) * 384 + hb;
                facc[i] = __builtin_amdgcn_mfma_f32_16x16x32_bf16(
                    *(const bf16x8*)(wr + lk), *(const bf16x8*)&m1[rb * 16 + l15][lk], facc[i], 0, 0, 0);
                facc[i] = __builtin_amdgcn_mfma_f32_16x16x32_bf16(
                    *(const bf16x8*)(wr + 32 + lk), *(const bf16x8*)&m1[rb * 16 + l15][32 + lk], facc[i], 0, 0, 0);
                facc[i] = __builtin_amdgcn_mfma_f32_16x16x32_bf16(
                    *(const bf16x8*)(wr + 64 + lk), *(const bf16x8*)&m1[rb * 16 + l15][64 + lk], facc[i], 0, 0, 0);
            }
            if (c < 3) __syncthreads();
        }

        // ---- Phase 7: out = h + fc2 + b2, float4 stores (unshift scatter) ----
        const int n = rb * 16 + l15;
        if (n < 49) {
            const int p = n / 7, q = n - 7 * p;
            int sr = wi * 7 + p + 3;  if (sr >= 56) sr -= 56;
            int scl = wj * 7 + q + 3; if (scl >= 56) scl -= 56;
            float* ob = out + ((size_t)b * 3136 + (size_t)(sr * 56 + scl)) * CDIM;
            #pragma unroll
            for (int i = 0; i < 3; ++i) {
                const int cb = (half + 2 * i) * 16 + g4;
                const float4 hv  = *(const float4*)&hbuf[n][cb];
                const float4 b2v = *(const float4*)(fc2_b + cb);
                float4 o4;
                o4.x = hv.x + facc[i][0] + b2v.x;
                o4.y = hv.y + facc[i][1] + b2v.y;
                o4.z = hv.z + facc[i][2] + b2v.z;
                o4.w = hv.w + facc[i][3] + b2v.w;
                *(float4*)(ob + cb) = o4;
            }
        }
    }
}

extern "C" void kernel_launch(void* const* d_in, const int* in_sizes, int n_in,
                              void* d_out, int out_size, void* d_ws, size_t ws_size,
                              hipStream_t stream) {
    (void)n_in; (void)out_size; (void)ws_size;
    const float* x        = (const float*)d_in[0];
    const float* attn_msk = (const float*)d_in[1];
    const float* ln1_g    = (const float*)d_in[2];
    const float* ln1_b    = (const float*)d_in[3];
    const float* qkv_w    = (const float*)d_in[4];
    const float* qkv_b    = (const float*)d_in[5];
    const float* rel_tab  = (const float*)d_in[6];
    const int*   rel_idx  = (const int*)d_in[7];
    const float* proj_w   = (const float*)d_in[8];
    const float* proj_b   = (const float*)d_in[9];
    const float* ln2_g    = (const float*)d_in[10];
    const float* ln2_b    = (const float*)d_in[11];
    const float* fc1_w    = (const float*)d_in[12];
    const float* fc1_b    = (const float*)d_in[13];
    const float* fc2_w    = (const float*)d_in[14];
    const float* fc2_b    = (const float*)d_in[15];
    float* out = (float*)d_out;
    unsigned short* wsb = (unsigned short*)d_ws;
    unsigned short* bmf = wsb + 110592;

    const int B = in_sizes[0] / (3136 * 96);   // 64

    conv_w_kernel<<<(110592 + 255) / 256, 256, 0, stream>>>(qkv_w, proj_w, fc1_w, fc2_w, wsb);
    build_bmfrag_kernel<<<196608 / 256, 256, 0, stream>>>(attn_msk, rel_tab, rel_idx, bmf);

    swin_fused<<<B * 64, 512, 0, stream>>>(
        x, ln1_g, ln1_b, qkv_b, proj_b, ln2_g, ln2_b, fc1_b, fc2_b,
        wsb, wsb + 27648, wsb + 36864, wsb + 73728, bmf, out);
}

// Round 11
// 325.644 us; speedup vs baseline: 1.2209x; 1.0009x over previous
//
#include <hip/hip_runtime.h>
#include <math.h>

// Swin block, fused bf16-MFMA kernel. R11: 4-wave blocks, strict wave-local
// token-block ownership -> 2 barriers total, no idle waves.
// B=64, H=W=56, C=96, WS=7, SS=3, NH=3, HD=32, N=49 (padded 64), nW=64.

#define CDIM 96
#define SCALE_QK 0.17677669529663687f  // 32^-0.5

typedef __attribute__((ext_vector_type(8))) short bf16x8;
typedef __attribute__((ext_vector_type(4))) float f32x4;
typedef __attribute__((ext_vector_type(2))) unsigned int u32x2;
typedef __attribute__((ext_vector_type(4))) unsigned int u32x4;

__device__ inline unsigned short f2b(float f) {
    union { float f; unsigned u; } v; v.f = f;
    unsigned r = v.u + 0x7FFF + ((v.u >> 16) & 1);   // RNE
    return (unsigned short)(r >> 16);
}
__device__ inline unsigned pkcvt(float a, float b) {   // low16=bf16(a), high16=bf16(b)
    unsigned d;
    asm("v_cvt_pk_bf16_f32 %0, %1, %2" : "=v"(d) : "v"(a), "v"(b));
    return d;
}
__device__ inline float bitsf(unsigned u) {
    union { unsigned u; float f; } v; v.u = u; return v.f;
}
__device__ inline bf16x8 mk8(unsigned d0, unsigned d1, unsigned d2, unsigned d3) {
    union { u32x4 u; bf16x8 h; } v;
    v.u = (u32x4){d0, d1, d2, d3};
    return v.h;
}

// ---------------- Kernel 0a: weights fp32 -> bf16 ----------------
__global__ __launch_bounds__(256) void conv_w_kernel(
    const float* __restrict__ qkv_w, const float* __restrict__ proj_w,
    const float* __restrict__ fc1_w, const float* __restrict__ fc2_w,
    unsigned short* __restrict__ ws)
{
    const int i = blockIdx.x * 256 + threadIdx.x;
    if (i < 27648)       ws[i] = f2b(qkv_w[i]);
    else if (i < 36864)  ws[i] = f2b(proj_w[i - 27648]);
    else if (i < 73728)  ws[i] = f2b(fc1_w[i - 36864]);
    else if (i < 110592) ws[i] = f2b(fc2_w[i - 73728]);
}

// ---------------- Kernel 0b: bias+mask in MFMA C-fragment layout, bf16 ----------------
__global__ __launch_bounds__(256) void build_bmfrag_kernel(
    const float* __restrict__ attn_mask, const float* __restrict__ rel_bias_table,
    const int* __restrict__ rel_index, unsigned short* __restrict__ bmf)
{
    const int i = blockIdx.x * 256 + threadIdx.x;   // 196608 total
    const int lane = i & 63;
    const int mt = (i >> 6) & 3;
    const int kt = (i >> 8) & 3;
    const int t3 = i >> 10;                          // widx*3 + h
    const int h = t3 % 3, widx = t3 / 3;
    const int q = mt * 16 + (lane & 15);
    const int kb = kt * 16 + (lane >> 4) * 4;
    float vv[4];
    #pragma unroll
    for (int rr = 0; rr < 4; ++rr) {
        const int k = kb + rr;
        float val = -1.0e30f;
        if (q < 49 && k < 49) {
            const int idx = q * 49 + k;
            val = rel_bias_table[rel_index[idx] * 3 + h] + attn_mask[widx * 2401 + idx];
        }
        vv[rr] = val;
    }
    u32x2 pw;
    pw.x = (unsigned)f2b(vv[0]) | ((unsigned)f2b(vv[1]) << 16);
    pw.y = (unsigned)f2b(vv[2]) | ((unsigned)f2b(vv[3]) << 16);
    *(u32x2*)(bmf + (size_t)i * 4) = pw;
}

// ---------------- Fused kernel (4 waves = 256 threads per 64-token window) ----------------
// LDS (40448 B): xt [64][104]u16 @0 | kss [64][104] @13312 | vs [96][72] @26624.
// Aliases: hbuf [64][100]f32 @13312 (over kss+vs, after attn barrier);
//          m1/xs [64][104]u16 @0 (over xt, wave-local rows only).
// Wave w owns token rows [16w,16w+16) in every phase -> only 2 barriers.
__global__ __launch_bounds__(256, 4) void swin_fused(
    const float* __restrict__ x,
    const float* __restrict__ ln1_g, const float* __restrict__ ln1_b,
    const float* __restrict__ qkv_b, const float* __restrict__ proj_b,
    const float* __restrict__ ln2_g, const float* __restrict__ ln2_b,
    const float* __restrict__ fc1_b, const float* __restrict__ fc2_b,
    const unsigned short* __restrict__ wqkv,   // [288][96] bf16
    const unsigned short* __restrict__ wproj,  // [96][96] bf16
    const unsigned short* __restrict__ wfc1,   // [384][96] bf16
    const unsigned short* __restrict__ wfc2,   // [96][384] bf16
    const unsigned short* __restrict__ bmfrag,
    float* __restrict__ out)
{
    __shared__ __align__(16) unsigned char smem[40448];
    unsigned short (*xt)[104]  = (unsigned short(*)[104])(smem);
    unsigned short (*kss)[104] = (unsigned short(*)[104])(smem + 13312);
    unsigned short (*vs)[72]   = (unsigned short(*)[72])(smem + 26624);
    unsigned short (*m1)[104]  = (unsigned short(*)[104])(smem);        // alias xt (own rows)
    float          (*hbuf)[100]= (float(*)[100])(smem + 13312);         // alias kss+vs
    unsigned short (*xs)[104]  = xt;

    const int w = blockIdx.x, b = w >> 6, widx = w & 63;
    const int wi = widx >> 3, wj = widx & 7;
    const int tid = threadIdx.x, wave = tid >> 6, lane = tid & 63;
    const int l15 = lane & 15, lk = (lane >> 4) * 8, g4 = (lane >> 4) * 4;
    const int rb = wave;                          // token-block owner
    const int srcA = ((lane >> 4) & 1) * 32 + l15;
    const int srcB = srcA + 16;
    const bool hi = (lane & 32) != 0;

    // ---- Phase 1: LN1 + shifted gather (roll -3,-3); 4 threads per row (own-wave rows) ----
    {
        const int n = tid >> 2, q4 = tid & 3;     // wave w writes rows [16w,16w+16)
        if (n < 49) {
            const int p = n / 7, qq = n - 7 * p;
            int sr = wi * 7 + p + 3;   if (sr >= 56) sr -= 56;
            int scl = wj * 7 + qq + 3; if (scl >= 56) scl -= 56;
            const float* xr = x + ((size_t)b * 3136 + (size_t)(sr * 56 + scl)) * CDIM + q4 * 24;
            float vals[24];
            float s = 0.f, ss2 = 0.f;
            #pragma unroll
            for (int i = 0; i < 6; ++i) {
                const float4 f = *(const float4*)(xr + i * 4);
                vals[i*4+0] = f.x; vals[i*4+1] = f.y; vals[i*4+2] = f.z; vals[i*4+3] = f.w;
                s += f.x + f.y + f.z + f.w;
                ss2 += f.x*f.x + f.y*f.y + f.z*f.z + f.w*f.w;
            }
            s += __shfl_xor(s, 1);  ss2 += __shfl_xor(ss2, 1);
            s += __shfl_xor(s, 2);  ss2 += __shfl_xor(ss2, 2);
            const float mean = s * (1.f / 96.f);
            const float rstd = rsqrtf(ss2 * (1.f / 96.f) - mean * mean + 1e-5f);
            #pragma unroll
            for (int v8 = 0; v8 < 3; ++v8) {
                u32x4 pv;
                #pragma unroll
                for (int d = 0; d < 4; ++d) {
                    const int e = v8 * 8 + d * 2;
                    const float ga = ln1_g[q4*24 + e],     gb2 = ln1_g[q4*24 + e + 1];
                    const float ba = ln1_b[q4*24 + e],     bb2 = ln1_b[q4*24 + e + 1];
                    pv[d] = pkcvt((vals[e]-mean)*rstd*ga + ba,
                                  (vals[e+1]-mean)*rstd*gb2 + bb2);
                }
                *(u32x4*)&xt[n][q4 * 24 + v8 * 8] = pv;
            }
        } else {
            const u32x4 z = {0u, 0u, 0u, 0u};
            #pragma unroll
            for (int v8 = 0; v8 < 3; ++v8) *(u32x4*)&xt[n][q4 * 24 + v8 * 8] = z;
        }
    }
    // no barrier: P2 reads only own-wave rows of xt

    // ---- Phase 2: qkv projection. K,V -> LDS; Q -> registers (C->A frag exchange) ----
    bf16x8 bq[3];
    {
        const bf16x8 bx0 = *(const bf16x8*)&xt[rb * 16 + l15][lk];
        const bf16x8 bx1 = *(const bf16x8*)&xt[rb * 16 + l15][32 + lk];
        const bf16x8 bx2 = *(const bf16x8*)&xt[rb * 16 + l15][64 + lk];
        // K swapped GEMM: all 6 feat-tiles (feats 96..191) for token block rb
        #pragma unroll
        for (int j = 0; j < 6; ++j) {
            const int qt = 6 + j;
            const unsigned short* wr = wqkv + (size_t)(qt * 16 + l15) * 96;
            f32x4 acc = {0.f, 0.f, 0.f, 0.f};
            acc = __builtin_amdgcn_mfma_f32_16x16x32_bf16(*(const bf16x8*)(wr + lk),      bx0, acc, 0, 0, 0);
            acc = __builtin_amdgcn_mfma_f32_16x16x32_bf16(*(const bf16x8*)(wr + 32 + lk), bx1, acc, 0, 0, 0);
            acc = __builtin_amdgcn_mfma_f32_16x16x32_bf16(*(const bf16x8*)(wr + 64 + lk), bx2, acc, 0, 0, 0);
            const int f0 = qt * 16 + g4;
            const float4 bias = *(const float4*)(qkv_b + f0);
            u32x2 pw;
            pw.x = pkcvt(acc[0] + bias.x, acc[1] + bias.y);
            pw.y = pkcvt(acc[2] + bias.z, acc[3] + bias.w);
            *(u32x2*)&kss[rb * 16 + l15][f0 - 96] = pw;
        }
        // V normal GEMM: all 6 vfeat-tiles, token rows rb
        #pragma unroll
        for (int vt = 0; vt < 6; ++vt) {
            const unsigned short* wr = wqkv + (size_t)(192 + vt * 16 + l15) * 96;
            f32x4 acc = {0.f, 0.f, 0.f, 0.f};
            acc = __builtin_amdgcn_mfma_f32_16x16x32_bf16(bx0, *(const bf16x8*)(wr + lk),      acc, 0, 0, 0);
            acc = __builtin_amdgcn_mfma_f32_16x16x32_bf16(bx1, *(const bf16x8*)(wr + 32 + lk), acc, 0, 0, 0);
            acc = __builtin_amdgcn_mfma_f32_16x16x32_bf16(bx2, *(const bf16x8*)(wr + 64 + lk), acc, 0, 0, 0);
            const float bias = qkv_b[192 + vt * 16 + l15];
            u32x2 pw;
            pw.x = pkcvt(acc[0] + bias, acc[1] + bias);
            pw.y = pkcvt(acc[2] + bias, acc[3] + bias);
            *(u32x2*)&vs[vt * 16 + l15][rb * 16 + g4] = pw;
        }
        // Q swapped GEMM, 3 heads; exchange C->A frag in registers
        #pragma unroll
        for (int h = 0; h < 3; ++h) {
            const unsigned short* wr0 = wqkv + (size_t)(h * 32 + l15) * 96;
            const unsigned short* wr1 = wqkv + (size_t)(h * 32 + 16 + l15) * 96;
            f32x4 a0v = {0.f,0.f,0.f,0.f}, a1v = {0.f,0.f,0.f,0.f};
            a0v = __builtin_amdgcn_mfma_f32_16x16x32_bf16(*(const bf16x8*)(wr0 + lk),      bx0, a0v, 0, 0, 0);
            a0v = __builtin_amdgcn_mfma_f32_16x16x32_bf16(*(const bf16x8*)(wr0 + 32 + lk), bx1, a0v, 0, 0, 0);
            a0v = __builtin_amdgcn_mfma_f32_16x16x32_bf16(*(const bf16x8*)(wr0 + 64 + lk), bx2, a0v, 0, 0, 0);
            a1v = __builtin_amdgcn_mfma_f32_16x16x32_bf16(*(const bf16x8*)(wr1 + lk),      bx0, a1v, 0, 0, 0);
            a1v = __builtin_amdgcn_mfma_f32_16x16x32_bf16(*(const bf16x8*)(wr1 + 32 + lk), bx1, a1v, 0, 0, 0);
            a1v = __builtin_amdgcn_mfma_f32_16x16x32_bf16(*(const bf16x8*)(wr1 + 64 + lk), bx2, a1v, 0, 0, 0);
            const float4 qb0 = *(const float4*)(qkv_b + h * 32 + g4);
            const float4 qb1 = *(const float4*)(qkv_b + h * 32 + 16 + g4);
            const unsigned pk00 = pkcvt((a0v[0] + qb0.x) * SCALE_QK, (a0v[1] + qb0.y) * SCALE_QK);
            const unsigned pk01 = pkcvt((a0v[2] + qb0.z) * SCALE_QK, (a0v[3] + qb0.w) * SCALE_QK);
            const unsigned pk10 = pkcvt((a1v[0] + qb1.x) * SCALE_QK, (a1v[1] + qb1.y) * SCALE_QK);
            const unsigned pk11 = pkcvt((a1v[2] + qb1.z) * SCALE_QK, (a1v[3] + qb1.w) * SCALE_QK);
            const unsigned aa0 = __shfl(pk00, srcA), aa1 = __shfl(pk01, srcA);
            const unsigned aa2 = __shfl(pk10, srcA), aa3 = __shfl(pk11, srcA);
            const unsigned bb0 = __shfl(pk00, srcB), bb1 = __shfl(pk01, srcB);
            const unsigned bb2 = __shfl(pk10, srcB), bb3 = __shfl(pk11, srcB);
            bq[h] = mk8(hi ? aa2 : aa0, hi ? aa3 : aa1, hi ? bb2 : bb0, hi ? bb3 : bb1);
        }
    }
    __syncthreads();    // BARRIER 1: kss/vs complete before cross-wave QK^T/PV reads

    // ---- Phase 3: swapped QK^T + register softmax + in-register P exchange + PV ----
    #pragma unroll
    for (int h = 0; h < 3; ++h) {
        const int mt = rb;
        const unsigned short* bmb = bmfrag + (size_t)(widx * 3 + h) * 4096 + mt * 256;
        f32x4 s[4];
        #pragma unroll
        for (int kt = 0; kt < 4; ++kt) {
            const bf16x8 ak = *(const bf16x8*)&kss[kt * 16 + l15][h * 32 + lk];
            const u32x2 cw = *(const u32x2*)(bmb + kt * 1024 + lane * 4);
            f32x4 c;
            c[0] = bitsf(cw.x << 16); c[1] = bitsf(cw.x & 0xffff0000u);
            c[2] = bitsf(cw.y << 16); c[3] = bitsf(cw.y & 0xffff0000u);
            s[kt] = __builtin_amdgcn_mfma_f32_16x16x32_bf16(ak, bq[h], c, 0, 0, 0);
        }
        float mx = s[0][0];
        #pragma unroll
        for (int kt = 0; kt < 4; ++kt)
            #pragma unroll
            for (int rr = 0; rr < 4; ++rr) mx = fmaxf(mx, s[kt][rr]);
        mx = fmaxf(mx, __shfl_xor(mx, 16));
        mx = fmaxf(mx, __shfl_xor(mx, 32));
        float sum = 0.f;
        #pragma unroll
        for (int kt = 0; kt < 4; ++kt)
            #pragma unroll
            for (int rr = 0; rr < 4; ++rr) {
                const float e = __expf(s[kt][rr] - mx);
                s[kt][rr] = e; sum += e;
            }
        sum += __shfl_xor(sum, 16);
        sum += __shfl_xor(sum, 32);
        const float inv = __fdividef(1.0f, sum);
        unsigned pk00 = pkcvt(s[0][0], s[0][1]), pk01 = pkcvt(s[0][2], s[0][3]);
        unsigned pk10 = pkcvt(s[1][0], s[1][1]), pk11 = pkcvt(s[1][2], s[1][3]);
        unsigned pk20 = pkcvt(s[2][0], s[2][1]), pk21 = pkcvt(s[2][2], s[2][3]);
        unsigned pk30 = pkcvt(s[3][0], s[3][1]), pk31 = pkcvt(s[3][2], s[3][3]);
        unsigned a0, a1, a2, a3, b0, b1, b2, b3;
        a0 = __shfl(pk00, srcA); a1 = __shfl(pk01, srcA);
        a2 = __shfl(pk10, srcA); a3 = __shfl(pk11, srcA);
        b0 = __shfl(pk00, srcB); b1 = __shfl(pk01, srcB);
        b2 = __shfl(pk10, srcB); b3 = __shfl(pk11, srcB);
        const bf16x8 pb0 = mk8(hi ? a2 : a0, hi ? a3 : a1, hi ? b2 : b0, hi ? b3 : b1);
        a0 = __shfl(pk20, srcA); a1 = __shfl(pk21, srcA);
        a2 = __shfl(pk30, srcA); a3 = __shfl(pk31, srcA);
        b0 = __shfl(pk20, srcB); b1 = __shfl(pk21, srcB);
        b2 = __shfl(pk30, srcB); b3 = __shfl(pk31, srcB);
        const bf16x8 pb1 = mk8(hi ? a2 : a0, hi ? a3 : a1, hi ? b2 : b0, hi ? b3 : b1);
        f32x4 o0 = {0.f,0.f,0.f,0.f}, o1 = {0.f,0.f,0.f,0.f};
        {
            const bf16x8 v00 = *(const bf16x8*)&vs[h * 32 + l15][lk];
            const bf16x8 v01 = *(const bf16x8*)&vs[h * 32 + l15][32 + lk];
            const bf16x8 v10 = *(const bf16x8*)&vs[h * 32 + 16 + l15][lk];
            const bf16x8 v11 = *(const bf16x8*)&vs[h * 32 + 16 + l15][32 + lk];
            o0 = __builtin_amdgcn_mfma_f32_16x16x32_bf16(v00, pb0, o0, 0, 0, 0);
            o0 = __builtin_amdgcn_mfma_f32_16x16x32_bf16(v01, pb1, o0, 0, 0, 0);
            o1 = __builtin_amdgcn_mfma_f32_16x16x32_bf16(v10, pb0, o1, 0, 0, 0);
            o1 = __builtin_amdgcn_mfma_f32_16x16x32_bf16(v11, pb1, o1, 0, 0, 0);
        }
        u32x2 ow;
        ow.x = pkcvt(o0[0] * inv, o0[1] * inv);
        ow.y = pkcvt(o0[2] * inv, o0[3] * inv);
        *(u32x2*)&xt[mt * 16 + l15][h * 32 + g4] = ow;
        ow.x = pkcvt(o1[0] * inv, o1[1] * inv);
        ow.y = pkcvt(o1[2] * inv, o1[3] * inv);
        *(u32x2*)&xt[mt * 16 + l15][h * 32 + 16 + g4] = ow;
    }
    __syncthreads();    // BARRIER 2: all kss/vs reads done before hbuf (alias) writes

    // ---- Phase 4: proj + x-residual -> hbuf (fp32); own rows; pad rows -> 0 ----
    {
        const bf16x8 a0 = *(const bf16x8*)&xt[rb * 16 + l15][lk];
        const bf16x8 a1 = *(const bf16x8*)&xt[rb * 16 + l15][32 + lk];
        const bf16x8 a2 = *(const bf16x8*)&xt[rb * 16 + l15][64 + lk];
        // precompute scatter bases for the 4 owned rows
        long sbase[4];
        #pragma unroll
        for (int rr = 0; rr < 4; ++rr) {
            const int n = rb * 16 + g4 + rr;
            if (n < 49) {
                const int p = n / 7, q = n - 7 * p;
                int sr = wi * 7 + p + 3;  if (sr >= 56) sr -= 56;
                int scl = wj * 7 + q + 3; if (scl >= 56) scl -= 56;
                sbase[rr] = ((long)b * 3136 + (long)(sr * 56 + scl)) * CDIM;
            } else sbase[rr] = -1;
        }
        #pragma unroll
        for (int nt = 0; nt < 6; ++nt) {
            const unsigned short* wr = wproj + (size_t)(nt * 16 + l15) * 96;
            f32x4 acc = {0.f, 0.f, 0.f, 0.f};
            acc = __builtin_amdgcn_mfma_f32_16x16x32_bf16(a0, *(const bf16x8*)(wr + lk),      acc, 0, 0, 0);
            acc = __builtin_amdgcn_mfma_f32_16x16x32_bf16(a1, *(const bf16x8*)(wr + 32 + lk), acc, 0, 0, 0);
            acc = __builtin_amdgcn_mfma_f32_16x16x32_bf16(a2, *(const bf16x8*)(wr + 64 + lk), acc, 0, 0, 0);
            const int colf = nt * 16 + l15;
            const float pb = proj_b[colf];
            #pragma unroll
            for (int rr = 0; rr < 4; ++rr) {
                const int n = rb * 16 + g4 + rr;
                if (sbase[rr] >= 0)
                    hbuf[n][colf] = acc[rr] + pb + x[sbase[rr] + colf];
                else
                    hbuf[n][colf] = 0.f;
            }
        }
    }
    // no barrier: P5 reads only own-wave hbuf rows

    // ---- Phase 5: LN2 hbuf -> xs (bf16); 4 threads per row, own-wave rows ----
    {
        const int n = tid >> 2, q4 = tid & 3;
        float vals[24];
        float s = 0.f, ss2 = 0.f;
        #pragma unroll
        for (int i = 0; i < 6; ++i) {
            const float4 f = *(const float4*)&hbuf[n][q4 * 24 + i * 4];
            vals[i*4+0] = f.x; vals[i*4+1] = f.y; vals[i*4+2] = f.z; vals[i*4+3] = f.w;
            s += f.x + f.y + f.z + f.w;
            ss2 += f.x*f.x + f.y*f.y + f.z*f.z + f.w*f.w;
        }
        s += __shfl_xor(s, 1);  ss2 += __shfl_xor(ss2, 1);
        s += __shfl_xor(s, 2);  ss2 += __shfl_xor(ss2, 2);
        const float mean = s * (1.f / 96.f);
        const float rstd = rsqrtf(ss2 * (1.f / 96.f) - mean * mean + 1e-5f);
        #pragma unroll
        for (int v8 = 0; v8 < 3; ++v8) {
            u32x4 pv;
            #pragma unroll
            for (int d = 0; d < 4; ++d) {
                const int e = v8 * 8 + d * 2;
                const float ga = ln2_g[q4*24 + e],  gb2 = ln2_g[q4*24 + e + 1];
                const float ba = ln2_b[q4*24 + e],  bb2 = ln2_b[q4*24 + e + 1];
                pv[d] = pkcvt((vals[e]-mean)*rstd*ga + ba,
                              (vals[e+1]-mean)*rstd*gb2 + bb2);
            }
            *(u32x4*)&xs[n][q4 * 24 + v8 * 8] = pv;
        }
    }
    // no barrier: P6 reads only own-wave xs rows

    // ---- Phase 6: MLP, 4 hidden chunks of 96; m1 aliases xs rows (own-wave only) ----
    {
        const bf16x8 mbx0 = *(const bf16x8*)&xs[rb * 16 + l15][lk];
        const bf16x8 mbx1 = *(const bf16x8*)&xs[rb * 16 + l15][32 + lk];
        const bf16x8 mbx2 = *(const bf16x8*)&xs[rb * 16 + l15][64 + lk];
        f32x4 facc[6] = {{0.f,0.f,0.f,0.f},{0.f,0.f,0.f,0.f},{0.f,0.f,0.f,0.f},
                         {0.f,0.f,0.f,0.f},{0.f,0.f,0.f,0.f},{0.f,0.f,0.f,0.f}};
        #pragma unroll
        for (int c = 0; c < 4; ++c) {
            const int hb = c * 96;
            // fc1 chunk + tanh-GELU -> m1[own rows][hid_local]
            #pragma unroll
            for (int ft = 0; ft < 6; ++ft) {
                const unsigned short* wr = wfc1 + (size_t)(hb + ft * 16 + l15) * 96;
                f32x4 acc = {0.f, 0.f, 0.f, 0.f};
                acc = __builtin_amdgcn_mfma_f32_16x16x32_bf16(*(const bf16x8*)(wr + lk),      mbx0, acc, 0, 0, 0);
                acc = __builtin_amdgcn_mfma_f32_16x16x32_bf16(*(const bf16x8*)(wr + 32 + lk), mbx1, acc, 0, 0, 0);
                acc = __builtin_amdgcn_mfma_f32_16x16x32_bf16(*(const bf16x8*)(wr + 64 + lk), mbx2, acc, 0, 0, 0);
                const int f0 = ft * 16 + g4;
                const float4 bias = *(const float4*)(fc1_b + hb + f0);
                const float* bp = &bias.x;
                float g[4];
                #pragma unroll
                for (int rr = 0; rr < 4; ++rr) {
                    const float u = acc[rr] + bp[rr];
                    const float u2 = u * u;
                    const float n2y = u * (-1.5957691216f - 0.0713548162f * u2);
                    g[rr] = __fdividef(u, 1.f + __expf(n2y));
                }
                u32x2 pw;
                pw.x = pkcvt(g[0], g[1]);
                pw.y = pkcvt(g[2], g[3]);
                *(u32x2*)&m1[rb * 16 + l15][f0] = pw;
            }
            // fc2 partials (same-wave RAW on m1, compiler-ordered; no barrier)
            #pragma unroll
            for (int ct = 0; ct < 6; ++ct) {
                const unsigned short* wr = wfc2 + (size_t)(ct * 16 + l15) * 384 + hb;
                facc[ct] = __builtin_amdgcn_mfma_f32_16x16x32_bf16(
                    *(const bf16x8*)(wr + lk), *(const bf16x8*)&m1[rb * 16 + l15][lk], facc[ct], 0, 0, 0);
                facc[ct] = __builtin_amdgcn_mfma_f32_16x16x32_bf16(
                    *(const bf16x8*)(wr + 32 + lk), *(const bf16x8*)&m1[rb * 16 + l15][32 + lk], facc[ct], 0, 0, 0);
                facc[ct] = __builtin_amdgcn_mfma_f32_16x16x32_bf16(
                    *(const bf16x8*)(wr + 64 + lk), *(const bf16x8*)&m1[rb * 16 + l15][64 + lk], facc[ct], 0, 0, 0);
            }
        }

        // ---- Phase 7: out = h + fc2 + b2, float4 stores (own row, unshift scatter) ----
        const int n = rb * 16 + l15;
        if (n < 49) {
            const int p = n / 7, q = n - 7 * p;
            int sr = wi * 7 + p + 3;  if (sr >= 56) sr -= 56;
            int scl = wj * 7 + q + 3; if (scl >= 56) scl -= 56;
            float* ob = out + ((size_t)b * 3136 + (size_t)(sr * 56 + scl)) * CDIM;
            #pragma unroll
            for (int ct = 0; ct < 6; ++ct) {
                const int cb = ct * 16 + g4;
                const float4 hv  = *(const float4*)&hbuf[n][cb];
                const float4 b2v = *(const float4*)(fc2_b + cb);
                float4 o4;
                o4.x = hv.x + facc[ct][0] + b2v.x;
                o4.y = hv.y + facc[ct][1] + b2v.y;
                o4.z = hv.z + facc[ct][2] + b2v.z;
                o4.w = hv.w + facc[ct][3] + b2v.w;
                *(float4*)(ob + cb) = o4;
            }
        }
    }
}

extern "C" void kernel_launch(void* const* d_in, const int* in_sizes, int n_in,
                              void* d_out, int out_size, void* d_ws, size_t ws_size,
                              hipStream_t stream) {
    (void)n_in; (void)out_size; (void)ws_size;
    const float* x        = (const float*)d_in[0];
    const float* attn_msk = (const float*)d_in[1];
    const float* ln1_g    = (const float*)d_in[2];
    const float* ln1_b    = (const float*)d_in[3];
    const float* qkv_w    = (const float*)d_in[4];
    const float* qkv_b    = (const float*)d_in[5];
    const float* rel_tab  = (const float*)d_in[6];
    const int*   rel_idx  = (const int*)d_in[7];
    const float* proj_w   = (const float*)d_in[8];
    const float* proj_b   = (const float*)d_in[9];
    const float* ln2_g    = (const float*)d_in[10];
    const float* ln2_b    = (const float*)d_in[11];
    const float* fc1_w    = (const float*)d_in[12];
    const float* fc1_b    = (const float*)d_in[13];
    const float* fc2_w    = (const float*)d_in[14];
    const float* fc2_b    = (const float*)d_in[15];
    float* out = (float*)d_out;
    unsigned short* wsb = (unsigned short*)d_ws;
    unsigned short* bmf = wsb + 110592;

    const int B = in_sizes[0] / (3136 * 96);   // 64

    conv_w_kernel<<<(110592 + 255) / 256, 256, 0, stream>>>(qkv_w, proj_w, fc1_w, fc2_w, wsb);
    build_bmfrag_kernel<<<196608 / 256, 256, 0, stream>>>(attn_msk, rel_tab, rel_idx, bmf);

    swin_fused<<<B * 64, 256, 0, stream>>>(
        x, ln1_g, ln1_b, qkv_b, proj_b, ln2_g, ln2_b, fc1_b, fc2_b,
        wsb, wsb + 27648, wsb + 36864, wsb + 73728, bmf, out);
}